// Round 7
// baseline (1905.280 us; speedup 1.0000x reference)
//
#include <hip/hip_runtime.h>

constexpr int H  = 16;
constexpr int HD = 48;
constexpr int D  = 768;    // H*HD
constexpr int DZ = 128;
constexpr int S  = 1024;
constexpr float EPS = 1e-5f;

__device__ __forceinline__ float sigmoidf_(float x) { return 1.f / (1.f + __expf(-x)); }

// ---------------------------------------------------------------------------
// Tiled f32 GEMM body: C[m][n] = sum_k A[m][k] * W[n][k]  (+bias[n], A gated by
// sigmoid(G) if G != nullptr). BM=BN=64, BK=16, 256 threads, 4x4 micro-tile.
// ---------------------------------------------------------------------------
__device__ __forceinline__ void gemm_tile(const float* __restrict__ A,
                                          const float* __restrict__ G,
                                          const float* __restrict__ W,
                                          const float* __restrict__ bias,
                                          float* __restrict__ C,
                                          const int bm, const int bn,
                                          const int N, const int K) {
  __shared__ float As[16][68];   // [k][m], row stride 68 floats (16B-aligned rows)
  __shared__ float Bs[16][68];   // [k][n]
  const int tid = threadIdx.x;
  const int tx = tid & 15, ty = tid >> 4;
  const int lr = tid >> 2;          // 0..63 tile row
  const int lk = (tid & 3) << 2;    // 0,4,8,12
  float acc[4][4] = {};
  for (int k0 = 0; k0 < K; k0 += 16) {
    float4 a = *reinterpret_cast<const float4*>(A + (size_t)(bm + lr) * K + (k0 + lk));
    if (G) {
      const float4 g = *reinterpret_cast<const float4*>(G + (size_t)(bm + lr) * K + (k0 + lk));
      a.x *= sigmoidf_(g.x); a.y *= sigmoidf_(g.y);
      a.z *= sigmoidf_(g.z); a.w *= sigmoidf_(g.w);
    }
    const float4 b = *reinterpret_cast<const float4*>(W + (size_t)(bn + lr) * K + (k0 + lk));
    As[lk + 0][lr] = a.x; As[lk + 1][lr] = a.y; As[lk + 2][lr] = a.z; As[lk + 3][lr] = a.w;
    Bs[lk + 0][lr] = b.x; Bs[lk + 1][lr] = b.y; Bs[lk + 2][lr] = b.z; Bs[lk + 3][lr] = b.w;
    __syncthreads();
#pragma unroll
    for (int k = 0; k < 16; ++k) {
      const float4 av = *reinterpret_cast<const float4*>(&As[k][ty << 2]);
      const float4 bv = *reinterpret_cast<const float4*>(&Bs[k][tx << 2]);
      const float am[4] = {av.x, av.y, av.z, av.w};
      const float bb[4] = {bv.x, bv.y, bv.z, bv.w};
#pragma unroll
      for (int i = 0; i < 4; ++i)
#pragma unroll
        for (int j = 0; j < 4; ++j) acc[i][j] += am[i] * bb[j];
    }
    __syncthreads();
  }
  float4 badd = make_float4(0.f, 0.f, 0.f, 0.f);
  if (bias) badd = *reinterpret_cast<const float4*>(bias + bn + (tx << 2));
#pragma unroll
  for (int i = 0; i < 4; ++i) {
    const int m = bm + (ty << 2) + i;
    float4 r;
    r.x = acc[i][0] + badd.x; r.y = acc[i][1] + badd.y;
    r.z = acc[i][2] + badd.z; r.w = acc[i][3] + badd.w;
    *reinterpret_cast<float4*>(C + (size_t)m * N + bn + (tx << 2)) = r;
  }
}

// Fused q/k/v/g projection: grid.x selects weight (4 x D/64), grid.y = S/64.
__global__ __launch_bounds__(256)
void qkvg_kernel(const float* __restrict__ s, const float* __restrict__ Wq,
                 const float* __restrict__ bq, const float* __restrict__ Wk,
                 const float* __restrict__ Wv, const float* __restrict__ Wg,
                 float* __restrict__ out) {
  const int nb = D / 64;
  const int wsel = blockIdx.x / nb;
  const int bn = (blockIdx.x % nb) * 64;
  const int bm = blockIdx.y * 64;
  const float* W = (wsel == 0) ? Wq : (wsel == 1) ? Wk : (wsel == 2) ? Wv : Wg;
  const float* bias = (wsel == 0) ? bq : nullptr;
  float* C = out + (size_t)wsel * S * D;
  gemm_tile(s, nullptr, W, bias, C, bm, bn, D, D);
}

// Gated output projection: out = (o * sigmoid(g)) @ Wo^T
__global__ __launch_bounds__(256)
void outproj_kernel(const float* __restrict__ o, const float* __restrict__ g,
                    const float* __restrict__ Wo, float* __restrict__ out) {
  gemm_tile(o, g, Wo, nullptr, out, blockIdx.y * 64, blockIdx.x * 64, D, D);
}

// ---------------------------------------------------------------------------
// pair-bias prep: WzW[h][c] = Wz[h][c]*ln_w[c]; S1[h] = sum_c WzW; S2[h] =
// sum_c ln_b[c]*Wz[h][c].  One small block.
// ---------------------------------------------------------------------------
__global__ __launch_bounds__(256)
void pb_prep_kernel(const float* __restrict__ Wz, const float* __restrict__ ln_w,
                    const float* __restrict__ ln_b, float* __restrict__ wzw,
                    float* __restrict__ s12) {
  const int t = threadIdx.x;
  for (int e = t; e < 16 * DZ; e += 256) wzw[e] = Wz[e] * ln_w[e & 127];
  if (t < 32) {
    const int h = t & 15;
    const float* coef = (t < 16) ? ln_w : ln_b;
    float a = 0.f;
    for (int c = 0; c < DZ; ++c) a += Wz[h * DZ + c] * coef[c];
    s12[t] = a;
  }
}

// ---------------------------------------------------------------------------
// Pair bias v6: 2-D register tile (4 rows x 4 heads per lane).
// Wave-autonomous 64-row chunk (1 chunk per wave, grid 4096x256).
// Per k-slice phase (ks = 0..3, 32 cols):
//   - 8 coalesced dwordx4 loads (lane -> row j*8+(l>>3), quad l&7); next-phase
//     slice prefetched into regs before compute.
//   - per-lane stats partials accumulate in regs across phases (lane owns the
//     same 8 (row, quad) slots every phase); 3x shfl_xor at the end.
//   - stage [64][36] f32 (stride 36 = 9 LDS slots; slot = 9r+kq mod 32 ->
//     compute reads 2-way max, staging writes 2-way max).
//   - compute: lane (rg = l>>2, hg = l&3) owns rows rg*4+.. x heads hg*4+..;
//     per kq: 4 z-reads + 4 w-reads (b128) feed 64 wave-FMAs.
// Weights [16][132] in LDS (slot = h + ks*8 + kq mod 32 -> conflict-free).
// Epilogue: LN affine folded (inv*(acc - mu*S1) + S2), transpose through
// reused staging LDS (stride 17), 16 coalesced 256B h-plane writes.
// ---------------------------------------------------------------------------
__global__ __launch_bounds__(256)
void pair_bias_kernel(const float* __restrict__ z, const float* __restrict__ wzw,
                      const float* __restrict__ s12, float* __restrict__ bias_out) {
  __shared__ float wl[16 * 132];       // 8.4 KB padded weights
  __shared__ float s12l[32];
  __shared__ float zs[4][64 * 36];     // 9.2 KB per wave staging (reused as T)
  __shared__ float mi[4][64][2];       // per-row (mu, inv)
  const int tid = threadIdx.x;
  const int lane = tid & 63;
  const int wv = tid >> 6;

  for (int e = tid; e < 16 * DZ; e += 256) wl[(e >> 7) * 132 + (e & 127)] = wzw[e];
  if (tid < 32) s12l[tid] = s12[tid];
  __syncthreads();   // only barrier

  float* Z = zs[wv];
  const int rg = lane >> 2, hg = lane & 3;      // compute roles
  const int lr8 = lane >> 3, lq = lane & 7;     // load roles
  const int chunk = blockIdx.x * 4 + wv;        // 16384 chunks of 64 rows
  const float* zc = z + (size_t)chunk * 64 * DZ;

  float acc[4][4] = {};
  float s1p[8] = {}, s2p[8] = {};

  // preload ks=0 slice
  float4 cur[8];
#pragma unroll
  for (int j = 0; j < 8; ++j)
    cur[j] = *reinterpret_cast<const float4*>(zc + (size_t)(j * 8 + lr8) * DZ + lq * 4);

#pragma unroll
  for (int ks = 0; ks < 4; ++ks) {
    // prefetch next slice
    float4 nxt[8];
    if (ks < 3) {
#pragma unroll
      for (int j = 0; j < 8; ++j)
        nxt[j] = *reinterpret_cast<const float4*>(
            zc + (size_t)(j * 8 + lr8) * DZ + (ks + 1) * 32 + lq * 4);
    }
    // stats partials + stage current slice
#pragma unroll
    for (int j = 0; j < 8; ++j) {
      const float4 v = cur[j];
      s1p[j] += (v.x + v.y) + (v.z + v.w);
      s2p[j] = fmaf(v.x, v.x, fmaf(v.y, v.y, fmaf(v.z, v.z, fmaf(v.w, v.w, s2p[j]))));
      *reinterpret_cast<float4*>(&Z[(j * 8 + lr8) * 36 + lq * 4]) = v;
    }
    // compute 4x4 tile over this k-slice
#pragma unroll
    for (int kq = 0; kq < 8; ++kq) {
      float4 zv[4], wvv[4];
#pragma unroll
      for (int i = 0; i < 4; ++i)
        zv[i] = *reinterpret_cast<const float4*>(&Z[(rg * 4 + i) * 36 + kq * 4]);
#pragma unroll
      for (int hj = 0; hj < 4; ++hj)
        wvv[hj] = *reinterpret_cast<const float4*>(&wl[(hg * 4 + hj) * 132 + ks * 32 + kq * 4]);
#pragma unroll
      for (int i = 0; i < 4; ++i)
#pragma unroll
        for (int hj = 0; hj < 4; ++hj)
          acc[i][hj] += zv[i].x * wvv[hj].x + zv[i].y * wvv[hj].y +
                        zv[i].z * wvv[hj].z + zv[i].w * wvv[hj].w;
    }
#pragma unroll
    for (int j = 0; j < 8; ++j) cur[j] = nxt[j];
  }

  // finalize row stats (reduce over the 8 lanes sharing each row)
#pragma unroll
  for (int j = 0; j < 8; ++j) {
    float a = s1p[j], b = s2p[j];
    a += __shfl_xor(a, 1); b += __shfl_xor(b, 1);
    a += __shfl_xor(a, 2); b += __shfl_xor(b, 2);
    a += __shfl_xor(a, 4); b += __shfl_xor(b, 4);
    if (lq == 0) {
      const float mu = a * (1.f / DZ);
      mi[wv][j * 8 + lr8][0] = mu;
      mi[wv][j * 8 + lr8][1] = rsqrtf(b * (1.f / DZ) - mu * mu + EPS);
    }
  }

  // epilogue: affine + transpose through reused staging LDS (stride 17)
#pragma unroll
  for (int i = 0; i < 4; ++i) {
    const int r = rg * 4 + i;
    const float mu = mi[wv][r][0];
    const float iv = mi[wv][r][1];
#pragma unroll
    for (int hj = 0; hj < 4; ++hj) {
      const int h = hg * 4 + hj;
      Z[r * 17 + h] = iv * (acc[i][hj] - mu * s12l[h]) + s12l[16 + h];
    }
  }
  const size_t p0 = (size_t)chunk * 64;
#pragma unroll
  for (int hh = 0; hh < 16; ++hh)
    bias_out[(size_t)hh * S * S + p0 + lane] = Z[lane * 17 + hh];
}

// ---------------------------------------------------------------------------
// Flash-style attention. Block = (head h, 64 query rows), 256 threads (16x16).
// ---------------------------------------------------------------------------
__global__ __launch_bounds__(256)
void attn_kernel(const float* __restrict__ q_ws, const float* __restrict__ k_ws,
                 const float* __restrict__ v_ws, const float* __restrict__ bias,
                 float* __restrict__ o_ws) {
  __shared__ float Qs[64][52];   // query rows (scaled), padded
  __shared__ float Ks[64][52];   // key rows, padded
  __shared__ float Vt[48][68];   // V transposed [d][t]
  __shared__ float Ps[64][68];   // probabilities tile

  const int tid = threadIdx.x;
  const int tx = tid & 15, ty = tid >> 4;
  const int h  = blockIdx.x >> 4;
  const int q0 = (blockIdx.x & 15) << 6;
  const float scale = 0.14433756729740643f;  // 1/sqrt(48)

  // stage Q (scaled): 64 rows x 12 float4
#pragma unroll
  for (int i = 0; i < 3; ++i) {
    const int f4 = tid + i * 256;
    const int r = f4 / 12, c4 = f4 % 12;
    float4 v = *reinterpret_cast<const float4*>(q_ws + (size_t)(q0 + r) * D + h * HD + c4 * 4);
    v.x *= scale; v.y *= scale; v.z *= scale; v.w *= scale;
    *reinterpret_cast<float4*>(&Qs[r][c4 * 4]) = v;
  }

  float m[4], l[4] = {0.f, 0.f, 0.f, 0.f};
  float acc[4][3] = {};
#pragma unroll
  for (int i = 0; i < 4; ++i) m[i] = -1e30f;

  for (int t0 = 0; t0 < S; t0 += 64) {
    // stage K tile (rows) and V tile (transposed)
#pragma unroll
    for (int i = 0; i < 3; ++i) {
      const int f4 = tid + i * 256;
      const int r = f4 / 12, c4 = f4 % 12;
      const float4 kv = *reinterpret_cast<const float4*>(k_ws + (size_t)(t0 + r) * D + h * HD + c4 * 4);
      *reinterpret_cast<float4*>(&Ks[r][c4 * 4]) = kv;
      const float4 vv = *reinterpret_cast<const float4*>(v_ws + (size_t)(t0 + r) * D + h * HD + c4 * 4);
      Vt[c4 * 4 + 0][r] = vv.x; Vt[c4 * 4 + 1][r] = vv.y;
      Vt[c4 * 4 + 2][r] = vv.z; Vt[c4 * 4 + 3][r] = vv.w;
    }
    __syncthreads();

    // S-tile: rows 4ty+i, cols 4tx+j, init from bias
    float s4[4][4];
#pragma unroll
    for (int i = 0; i < 4; ++i) {
      const float4 b4 = *reinterpret_cast<const float4*>(
          bias + ((size_t)h * S + (q0 + 4 * ty + i)) * S + t0 + 4 * tx);
      s4[i][0] = b4.x; s4[i][1] = b4.y; s4[i][2] = b4.z; s4[i][3] = b4.w;
    }
#pragma unroll
    for (int k4 = 0; k4 < 12; ++k4) {
      float4 qv[4], kv[4];
#pragma unroll
      for (int i = 0; i < 4; ++i) qv[i] = *reinterpret_cast<const float4*>(&Qs[4 * ty + i][k4 * 4]);
#pragma unroll
      for (int j = 0; j < 4; ++j) kv[j] = *reinterpret_cast<const float4*>(&Ks[4 * tx + j][k4 * 4]);
#pragma unroll
      for (int i = 0; i < 4; ++i)
#pragma unroll
        for (int j = 0; j < 4; ++j)
          s4[i][j] += qv[i].x * kv[j].x + qv[i].y * kv[j].y +
                      qv[i].z * kv[j].z + qv[i].w * kv[j].w;
    }

    // online softmax (row groups = 16 tx lanes; shfl_xor stays in-group)
#pragma unroll
    for (int i = 0; i < 4; ++i) {
      float tmax = fmaxf(fmaxf(s4[i][0], s4[i][1]), fmaxf(s4[i][2], s4[i][3]));
#pragma unroll
      for (int off = 8; off >= 1; off >>= 1) tmax = fmaxf(tmax, __shfl_xor(tmax, off));
      const float mn = fmaxf(m[i], tmax);
      const float fac = __expf(m[i] - mn);
      float p0 = __expf(s4[i][0] - mn), p1 = __expf(s4[i][1] - mn);
      float p2 = __expf(s4[i][2] - mn), p3 = __expf(s4[i][3] - mn);
      l[i] = l[i] * fac + (p0 + p1 + p2 + p3);   // per-thread partial sum
      acc[i][0] *= fac; acc[i][1] *= fac; acc[i][2] *= fac;
      m[i] = mn;
      *reinterpret_cast<float4*>(&Ps[4 * ty + i][4 * tx]) = make_float4(p0, p1, p2, p3);
    }
    __syncthreads();

    // PV: rows 4ty+i, dims 3tx+j, vectorized over t-quads
#pragma unroll
    for (int t4 = 0; t4 < 16; ++t4) {
      float4 pv[4], vv[3];
#pragma unroll
      for (int i = 0; i < 4; ++i) pv[i] = *reinterpret_cast<const float4*>(&Ps[4 * ty + i][4 * t4]);
#pragma unroll
      for (int j = 0; j < 3; ++j) vv[j] = *reinterpret_cast<const float4*>(&Vt[3 * tx + j][4 * t4]);
#pragma unroll
      for (int i = 0; i < 4; ++i)
#pragma unroll
        for (int j = 0; j < 3; ++j)
          acc[i][j] += pv[i].x * vv[j].x + pv[i].y * vv[j].y +
                       pv[i].z * vv[j].z + pv[i].w * vv[j].w;
    }
    __syncthreads();
  }

  // finalize: full row sum of l across tx group, normalize, write
#pragma unroll
  for (int i = 0; i < 4; ++i) {
    float lt = l[i];
#pragma unroll
    for (int off = 8; off >= 1; off >>= 1) lt += __shfl_xor(lt, off);
    const float rl = 1.f / lt;
    float* op = o_ws + (size_t)(q0 + 4 * ty + i) * D + h * HD;
#pragma unroll
    for (int j = 0; j < 3; ++j) op[3 * tx + j] = acc[i][j] * rl;
  }
}

extern "C" void kernel_launch(void* const* d_in, const int* in_sizes, int n_in,
                              void* d_out, int out_size, void* d_ws, size_t ws_size,
                              hipStream_t stream) {
  const float* s    = (const float*)d_in[0];
  const float* z    = (const float*)d_in[1];
  const float* Wq   = (const float*)d_in[2];
  const float* bq   = (const float*)d_in[3];
  const float* Wk   = (const float*)d_in[4];
  const float* Wv   = (const float*)d_in[5];
  const float* Wg   = (const float*)d_in[6];
  const float* ln_w = (const float*)d_in[7];
  const float* ln_b = (const float*)d_in[8];
  const float* Wz   = (const float*)d_in[9];
  const float* Wo   = (const float*)d_in[10];
  float* out = (float*)d_out;

  // workspace (floats): q,k,v,g,o = 5*S*D; bias = H*S*S; wzw = 2048; s12 = 32
  float* q_ws    = (float*)d_ws;
  float* k_ws    = q_ws + (size_t)S * D;
  float* v_ws    = k_ws + (size_t)S * D;
  float* g_ws    = v_ws + (size_t)S * D;
  float* o_ws    = g_ws + (size_t)S * D;
  float* bias_ws = o_ws + (size_t)S * D;
  float* wzw_ws  = bias_ws + (size_t)H * S * S;
  float* s12_ws  = wzw_ws + 16 * DZ;

  // 1) fused QKVG projections
  qkvg_kernel<<<dim3(4 * (D / 64), S / 64), 256, 0, stream>>>(s, Wq, bq, Wk, Wv, Wg, q_ws);
  // 2) pair bias (LN folded): prep then streaming kernel
  pb_prep_kernel<<<1, 256, 0, stream>>>(Wz, ln_w, ln_b, wzw_ws, s12_ws);
  pair_bias_kernel<<<4096, 256, 0, stream>>>(z, wzw_ws, s12_ws, bias_ws);
  // 3) flash attention
  attn_kernel<<<dim3(H * (S / 64)), 256, 0, stream>>>(q_ws, k_ws, v_ws, bias_ws, o_ws);
  // 4) gate + output projection
  outproj_kernel<<<dim3(D / 64, S / 64), 256, 0, stream>>>(o_ws, g_ws, Wo, out);
}

// Round 8
// 1669.904 us; speedup vs baseline: 1.1410x; 1.1410x over previous
//
#include <hip/hip_runtime.h>

constexpr int H  = 16;
constexpr int HD = 48;
constexpr int D  = 768;    // H*HD
constexpr int DZ = 128;
constexpr int S  = 1024;
constexpr float EPS = 1e-5f;

__device__ __forceinline__ float sigmoidf_(float x) { return 1.f / (1.f + __expf(-x)); }

// ---------------------------------------------------------------------------
// Tiled f32 GEMM body: C[m][n] = sum_k A[m][k] * W[n][k]  (+bias[n], A gated by
// sigmoid(G) if G != nullptr). BM=BN=64, BK=16, 256 threads, 4x4 micro-tile.
// ---------------------------------------------------------------------------
__device__ __forceinline__ void gemm_tile(const float* __restrict__ A,
                                          const float* __restrict__ G,
                                          const float* __restrict__ W,
                                          const float* __restrict__ bias,
                                          float* __restrict__ C,
                                          const int bm, const int bn,
                                          const int N, const int K) {
  __shared__ float As[16][68];   // [k][m], row stride 68 floats (16B-aligned rows)
  __shared__ float Bs[16][68];   // [k][n]
  const int tid = threadIdx.x;
  const int tx = tid & 15, ty = tid >> 4;
  const int lr = tid >> 2;          // 0..63 tile row
  const int lk = (tid & 3) << 2;    // 0,4,8,12
  float acc[4][4] = {};
  for (int k0 = 0; k0 < K; k0 += 16) {
    float4 a = *reinterpret_cast<const float4*>(A + (size_t)(bm + lr) * K + (k0 + lk));
    if (G) {
      const float4 g = *reinterpret_cast<const float4*>(G + (size_t)(bm + lr) * K + (k0 + lk));
      a.x *= sigmoidf_(g.x); a.y *= sigmoidf_(g.y);
      a.z *= sigmoidf_(g.z); a.w *= sigmoidf_(g.w);
    }
    const float4 b = *reinterpret_cast<const float4*>(W + (size_t)(bn + lr) * K + (k0 + lk));
    As[lk + 0][lr] = a.x; As[lk + 1][lr] = a.y; As[lk + 2][lr] = a.z; As[lk + 3][lr] = a.w;
    Bs[lk + 0][lr] = b.x; Bs[lk + 1][lr] = b.y; Bs[lk + 2][lr] = b.z; Bs[lk + 3][lr] = b.w;
    __syncthreads();
#pragma unroll
    for (int k = 0; k < 16; ++k) {
      const float4 av = *reinterpret_cast<const float4*>(&As[k][ty << 2]);
      const float4 bv = *reinterpret_cast<const float4*>(&Bs[k][tx << 2]);
      const float am[4] = {av.x, av.y, av.z, av.w};
      const float bb[4] = {bv.x, bv.y, bv.z, bv.w};
#pragma unroll
      for (int i = 0; i < 4; ++i)
#pragma unroll
        for (int j = 0; j < 4; ++j) acc[i][j] += am[i] * bb[j];
    }
    __syncthreads();
  }
  float4 badd = make_float4(0.f, 0.f, 0.f, 0.f);
  if (bias) badd = *reinterpret_cast<const float4*>(bias + bn + (tx << 2));
#pragma unroll
  for (int i = 0; i < 4; ++i) {
    const int m = bm + (ty << 2) + i;
    float4 r;
    r.x = acc[i][0] + badd.x; r.y = acc[i][1] + badd.y;
    r.z = acc[i][2] + badd.z; r.w = acc[i][3] + badd.w;
    *reinterpret_cast<float4*>(C + (size_t)m * N + bn + (tx << 2)) = r;
  }
}

// Fused q/k/v/g projection: grid.x selects weight (4 x D/64), grid.y = S/64.
__global__ __launch_bounds__(256)
void qkvg_kernel(const float* __restrict__ s, const float* __restrict__ Wq,
                 const float* __restrict__ bq, const float* __restrict__ Wk,
                 const float* __restrict__ Wv, const float* __restrict__ Wg,
                 float* __restrict__ out) {
  const int nb = D / 64;
  const int wsel = blockIdx.x / nb;
  const int bn = (blockIdx.x % nb) * 64;
  const int bm = blockIdx.y * 64;
  const float* W = (wsel == 0) ? Wq : (wsel == 1) ? Wk : (wsel == 2) ? Wv : Wg;
  const float* bias = (wsel == 0) ? bq : nullptr;
  float* C = out + (size_t)wsel * S * D;
  gemm_tile(s, nullptr, W, bias, C, bm, bn, D, D);
}

// Gated output projection: out = (o * sigmoid(g)) @ Wo^T
__global__ __launch_bounds__(256)
void outproj_kernel(const float* __restrict__ o, const float* __restrict__ g,
                    const float* __restrict__ Wo, float* __restrict__ out) {
  gemm_tile(o, g, Wo, nullptr, out, blockIdx.y * 64, blockIdx.x * 64, D, D);
}

// ---------------------------------------------------------------------------
// pair-bias prep: WzW[h][c] = Wz[h][c]*ln_w[c]; S1[h] = sum_c WzW; S2[h] =
// sum_c ln_b[c]*Wz[h][c].  One small block.
// ---------------------------------------------------------------------------
__global__ __launch_bounds__(256)
void pb_prep_kernel(const float* __restrict__ Wz, const float* __restrict__ ln_w,
                    const float* __restrict__ ln_b, float* __restrict__ wzw,
                    float* __restrict__ s12) {
  const int t = threadIdx.x;
  for (int e = t; e < 16 * DZ; e += 256) wzw[e] = Wz[e] * ln_w[e & 127];
  if (t < 32) {
    const int h = t & 15;
    const float* coef = (t < 16) ? ln_w : ln_b;
    float a = 0.f;
    for (int c = 0; c < DZ; ++c) a += Wz[h * DZ + c] * coef[c];
    s12[t] = a;
  }
}

// ---------------------------------------------------------------------------
// Pair bias v7: v6 (2-D register tile, 4 rows x 4 heads per lane) with the
// two measured bugs fixed:
//  (1) NO register prefetch (v6 spilled: VGPR=256, 3.4GB scratch). Per slice:
//      8 coalesced loads -> stats+stage -> compute. Next slice's loads are
//      independent, scheduler hoists them; 3 waves/SIMD add TLP.
//  (2) compute rows rg + 16*i (stride 1 in rg). Bank math: slot 36r mod 32
//      = 4r mod 32 -> rows rg and rg+8 share a bank-quad = 2-way (free).
//      v6's rg*4+i put 8 rows per quad = 8-way (3.7M conflicts measured).
// Load pattern unchanged (8 full 128B lines per instr). Weights [16][132]
// broadcast 4-distinct-address reads. Epilogue transpose through reused
// staging LDS (stride 17; 17*lane mod 32 bijective -> conflict-free).
// ---------------------------------------------------------------------------
__global__ __launch_bounds__(256)
void pair_bias_kernel(const float* __restrict__ z, const float* __restrict__ wzw,
                      const float* __restrict__ s12, float* __restrict__ bias_out) {
  __shared__ float wl[16 * 132];       // 8.25 KB padded weights
  __shared__ float s12l[32];
  __shared__ float zs[4][64 * 36];     // 9 KB per-wave staging (reused as T)
  __shared__ float mi[4][64][2];       // per-row (mu, inv)
  const int tid = threadIdx.x;
  const int lane = tid & 63;
  const int wv = tid >> 6;

  for (int e = tid; e < 16 * DZ; e += 256) wl[(e >> 7) * 132 + (e & 127)] = wzw[e];
  if (tid < 32) s12l[tid] = s12[tid];
  __syncthreads();   // only barrier

  float* Z = zs[wv];
  const int rg = lane >> 2, hg = lane & 3;      // compute roles
  const int lr8 = lane >> 3, lq = lane & 7;     // load roles
  const int chunk = blockIdx.x * 4 + wv;        // 16384 chunks of 64 rows
  const float* zc = z + (size_t)chunk * 64 * DZ;

  float acc[4][4] = {};
  float s1p[8] = {}, s2p[8] = {};

#pragma unroll
  for (int ks = 0; ks < 4; ++ks) {
    // load slice (8 coalesced dwordx4: 8 rows x 32 c per instr), stats, stage
#pragma unroll
    for (int j = 0; j < 8; ++j) {
      const float4 v = *reinterpret_cast<const float4*>(
          zc + (size_t)(j * 8 + lr8) * DZ + ks * 32 + lq * 4);
      s1p[j] += (v.x + v.y) + (v.z + v.w);
      s2p[j] = fmaf(v.x, v.x, fmaf(v.y, v.y, fmaf(v.z, v.z, fmaf(v.w, v.w, s2p[j]))));
      *reinterpret_cast<float4*>(&Z[(j * 8 + lr8) * 36 + lq * 4]) = v;
    }
    // compute 4x4 tile over this k-slice (rows rg+16i, heads hg*4+hj)
#pragma unroll
    for (int kq = 0; kq < 8; ++kq) {
      float4 zv[4], wvv[4];
#pragma unroll
      for (int i = 0; i < 4; ++i)
        zv[i] = *reinterpret_cast<const float4*>(&Z[(rg + 16 * i) * 36 + kq * 4]);
#pragma unroll
      for (int hj = 0; hj < 4; ++hj)
        wvv[hj] = *reinterpret_cast<const float4*>(&wl[(hg * 4 + hj) * 132 + ks * 32 + kq * 4]);
#pragma unroll
      for (int i = 0; i < 4; ++i)
#pragma unroll
        for (int hj = 0; hj < 4; ++hj)
          acc[i][hj] += zv[i].x * wvv[hj].x + zv[i].y * wvv[hj].y +
                        zv[i].z * wvv[hj].z + zv[i].w * wvv[hj].w;
    }
  }

  // finalize row stats (reduce over the 8 lanes sharing each row)
#pragma unroll
  for (int j = 0; j < 8; ++j) {
    float a = s1p[j], b = s2p[j];
    a += __shfl_xor(a, 1); b += __shfl_xor(b, 1);
    a += __shfl_xor(a, 2); b += __shfl_xor(b, 2);
    a += __shfl_xor(a, 4); b += __shfl_xor(b, 4);
    if (lq == 0) {
      const float mu = a * (1.f / DZ);
      mi[wv][j * 8 + lr8][0] = mu;
      mi[wv][j * 8 + lr8][1] = rsqrtf(b * (1.f / DZ) - mu * mu + EPS);
    }
  }

  // epilogue: affine + transpose through reused staging LDS (stride 17)
#pragma unroll
  for (int i = 0; i < 4; ++i) {
    const int r = rg + 16 * i;
    const float mu = mi[wv][r][0];
    const float iv = mi[wv][r][1];
#pragma unroll
    for (int hj = 0; hj < 4; ++hj) {
      const int h = hg * 4 + hj;
      Z[r * 17 + h] = iv * (acc[i][hj] - mu * s12l[h]) + s12l[16 + h];
    }
  }
  const size_t p0 = (size_t)chunk * 64;
#pragma unroll
  for (int hh = 0; hh < 16; ++hh)
    bias_out[(size_t)hh * S * S + p0 + lane] = Z[lane * 17 + hh];
}

// ---------------------------------------------------------------------------
// Flash-style attention. Block = (head h, 64 query rows), 256 threads (16x16).
// ---------------------------------------------------------------------------
__global__ __launch_bounds__(256)
void attn_kernel(const float* __restrict__ q_ws, const float* __restrict__ k_ws,
                 const float* __restrict__ v_ws, const float* __restrict__ bias,
                 float* __restrict__ o_ws) {
  __shared__ float Qs[64][52];   // query rows (scaled), padded
  __shared__ float Ks[64][52];   // key rows, padded
  __shared__ float Vt[48][68];   // V transposed [d][t]
  __shared__ float Ps[64][68];   // probabilities tile

  const int tid = threadIdx.x;
  const int tx = tid & 15, ty = tid >> 4;
  const int h  = blockIdx.x >> 4;
  const int q0 = (blockIdx.x & 15) << 6;
  const float scale = 0.14433756729740643f;  // 1/sqrt(48)

  // stage Q (scaled): 64 rows x 12 float4
#pragma unroll
  for (int i = 0; i < 3; ++i) {
    const int f4 = tid + i * 256;
    const int r = f4 / 12, c4 = f4 % 12;
    float4 v = *reinterpret_cast<const float4*>(q_ws + (size_t)(q0 + r) * D + h * HD + c4 * 4);
    v.x *= scale; v.y *= scale; v.z *= scale; v.w *= scale;
    *reinterpret_cast<float4*>(&Qs[r][c4 * 4]) = v;
  }

  float m[4], l[4] = {0.f, 0.f, 0.f, 0.f};
  float acc[4][3] = {};
#pragma unroll
  for (int i = 0; i < 4; ++i) m[i] = -1e30f;

  for (int t0 = 0; t0 < S; t0 += 64) {
    // stage K tile (rows) and V tile (transposed)
#pragma unroll
    for (int i = 0; i < 3; ++i) {
      const int f4 = tid + i * 256;
      const int r = f4 / 12, c4 = f4 % 12;
      const float4 kv = *reinterpret_cast<const float4*>(k_ws + (size_t)(t0 + r) * D + h * HD + c4 * 4);
      *reinterpret_cast<float4*>(&Ks[r][c4 * 4]) = kv;
      const float4 vv = *reinterpret_cast<const float4*>(v_ws + (size_t)(t0 + r) * D + h * HD + c4 * 4);
      Vt[c4 * 4 + 0][r] = vv.x; Vt[c4 * 4 + 1][r] = vv.y;
      Vt[c4 * 4 + 2][r] = vv.z; Vt[c4 * 4 + 3][r] = vv.w;
    }
    __syncthreads();

    // S-tile: rows 4ty+i, cols 4tx+j, init from bias
    float s4[4][4];
#pragma unroll
    for (int i = 0; i < 4; ++i) {
      const float4 b4 = *reinterpret_cast<const float4*>(
          bias + ((size_t)h * S + (q0 + 4 * ty + i)) * S + t0 + 4 * tx);
      s4[i][0] = b4.x; s4[i][1] = b4.y; s4[i][2] = b4.z; s4[i][3] = b4.w;
    }
#pragma unroll
    for (int k4 = 0; k4 < 12; ++k4) {
      float4 qv[4], kv[4];
#pragma unroll
      for (int i = 0; i < 4; ++i) qv[i] = *reinterpret_cast<const float4*>(&Qs[4 * ty + i][k4 * 4]);
#pragma unroll
      for (int j = 0; j < 4; ++j) kv[j] = *reinterpret_cast<const float4*>(&Ks[4 * tx + j][k4 * 4]);
#pragma unroll
      for (int i = 0; i < 4; ++i)
#pragma unroll
        for (int j = 0; j < 4; ++j)
          s4[i][j] += qv[i].x * kv[j].x + qv[i].y * kv[j].y +
                      qv[i].z * kv[j].z + qv[i].w * kv[j].w;
    }

    // online softmax (row groups = 16 tx lanes; shfl_xor stays in-group)
#pragma unroll
    for (int i = 0; i < 4; ++i) {
      float tmax = fmaxf(fmaxf(s4[i][0], s4[i][1]), fmaxf(s4[i][2], s4[i][3]));
#pragma unroll
      for (int off = 8; off >= 1; off >>= 1) tmax = fmaxf(tmax, __shfl_xor(tmax, off));
      const float mn = fmaxf(m[i], tmax);
      const float fac = __expf(m[i] - mn);
      float p0 = __expf(s4[i][0] - mn), p1 = __expf(s4[i][1] - mn);
      float p2 = __expf(s4[i][2] - mn), p3 = __expf(s4[i][3] - mn);
      l[i] = l[i] * fac + (p0 + p1 + p2 + p3);   // per-thread partial sum
      acc[i][0] *= fac; acc[i][1] *= fac; acc[i][2] *= fac;
      m[i] = mn;
      *reinterpret_cast<float4*>(&Ps[4 * ty + i][4 * tx]) = make_float4(p0, p1, p2, p3);
    }
    __syncthreads();

    // PV: rows 4ty+i, dims 3tx+j, vectorized over t-quads
#pragma unroll
    for (int t4 = 0; t4 < 16; ++t4) {
      float4 pv[4], vv[3];
#pragma unroll
      for (int i = 0; i < 4; ++i) pv[i] = *reinterpret_cast<const float4*>(&Ps[4 * ty + i][4 * t4]);
#pragma unroll
      for (int j = 0; j < 3; ++j) vv[j] = *reinterpret_cast<const float4*>(&Vt[3 * tx + j][4 * t4]);
#pragma unroll
      for (int i = 0; i < 4; ++i)
#pragma unroll
        for (int j = 0; j < 3; ++j)
          acc[i][j] += pv[i].x * vv[j].x + pv[i].y * vv[j].y +
                       pv[i].z * vv[j].z + pv[i].w * vv[j].w;
    }
    __syncthreads();
  }

  // finalize: full row sum of l across tx group, normalize, write
#pragma unroll
  for (int i = 0; i < 4; ++i) {
    float lt = l[i];
#pragma unroll
    for (int off = 8; off >= 1; off >>= 1) lt += __shfl_xor(lt, off);
    const float rl = 1.f / lt;
    float* op = o_ws + (size_t)(q0 + 4 * ty + i) * D + h * HD;
#pragma unroll
    for (int j = 0; j < 3; ++j) op[3 * tx + j] = acc[i][j] * rl;
  }
}

extern "C" void kernel_launch(void* const* d_in, const int* in_sizes, int n_in,
                              void* d_out, int out_size, void* d_ws, size_t ws_size,
                              hipStream_t stream) {
  const float* s    = (const float*)d_in[0];
  const float* z    = (const float*)d_in[1];
  const float* Wq   = (const float*)d_in[2];
  const float* bq   = (const float*)d_in[3];
  const float* Wk   = (const float*)d_in[4];
  const float* Wv   = (const float*)d_in[5];
  const float* Wg   = (const float*)d_in[6];
  const float* ln_w = (const float*)d_in[7];
  const float* ln_b = (const float*)d_in[8];
  const float* Wz   = (const float*)d_in[9];
  const float* Wo   = (const float*)d_in[10];
  float* out = (float*)d_out;

  // workspace (floats): q,k,v,g,o = 5*S*D; bias = H*S*S; wzw = 2048; s12 = 32
  float* q_ws    = (float*)d_ws;
  float* k_ws    = q_ws + (size_t)S * D;
  float* v_ws    = k_ws + (size_t)S * D;
  float* g_ws    = v_ws + (size_t)S * D;
  float* o_ws    = g_ws + (size_t)S * D;
  float* bias_ws = o_ws + (size_t)S * D;
  float* wzw_ws  = bias_ws + (size_t)H * S * S;
  float* s12_ws  = wzw_ws + 16 * DZ;

  // 1) fused QKVG projections
  qkvg_kernel<<<dim3(4 * (D / 64), S / 64), 256, 0, stream>>>(s, Wq, bq, Wk, Wv, Wg, q_ws);
  // 2) pair bias (LN folded): prep then streaming kernel
  pb_prep_kernel<<<1, 256, 0, stream>>>(Wz, ln_w, ln_b, wzw_ws, s12_ws);
  pair_bias_kernel<<<4096, 256, 0, stream>>>(z, wzw_ws, s12_ws, bias_ws);
  // 3) flash attention
  attn_kernel<<<dim3(H * (S / 64)), 256, 0, stream>>>(q_ws, k_ws, v_ws, bias_ws, o_ws);
  // 4) gate + output projection
  outproj_kernel<<<dim3(D / 64, S / 64), 256, 0, stream>>>(o_ws, g_ws, Wo, out);
}

// Round 9
// 493.066 us; speedup vs baseline: 3.8642x; 3.3868x over previous
//
#include <hip/hip_runtime.h>

constexpr int H  = 16;
constexpr int HD = 48;
constexpr int D  = 768;    // H*HD
constexpr int DZ = 128;
constexpr int S  = 1024;
constexpr float EPS = 1e-5f;

__device__ __forceinline__ float sigmoidf_(float x) { return 1.f / (1.f + __expf(-x)); }

// ---------------------------------------------------------------------------
// Tiled f32 GEMM body: C[m][n] = sum_k A[m][k] * W[n][k]  (+bias[n], A gated by
// sigmoid(G) if G != nullptr). BM=BN=64, BK=16, 256 threads, 4x4 micro-tile.
// ---------------------------------------------------------------------------
__device__ __forceinline__ void gemm_tile(const float* __restrict__ A,
                                          const float* __restrict__ G,
                                          const float* __restrict__ W,
                                          const float* __restrict__ bias,
                                          float* __restrict__ C,
                                          const int bm, const int bn,
                                          const int N, const int K) {
  __shared__ float As[16][68];   // [k][m], row stride 68 floats (16B-aligned rows)
  __shared__ float Bs[16][68];   // [k][n]
  const int tid = threadIdx.x;
  const int tx = tid & 15, ty = tid >> 4;
  const int lr = tid >> 2;          // 0..63 tile row
  const int lk = (tid & 3) << 2;    // 0,4,8,12
  float acc[4][4] = {};
  for (int k0 = 0; k0 < K; k0 += 16) {
    float4 a = *reinterpret_cast<const float4*>(A + (size_t)(bm + lr) * K + (k0 + lk));
    if (G) {
      const float4 g = *reinterpret_cast<const float4*>(G + (size_t)(bm + lr) * K + (k0 + lk));
      a.x *= sigmoidf_(g.x); a.y *= sigmoidf_(g.y);
      a.z *= sigmoidf_(g.z); a.w *= sigmoidf_(g.w);
    }
    const float4 b = *reinterpret_cast<const float4*>(W + (size_t)(bn + lr) * K + (k0 + lk));
    As[lk + 0][lr] = a.x; As[lk + 1][lr] = a.y; As[lk + 2][lr] = a.z; As[lk + 3][lr] = a.w;
    Bs[lk + 0][lr] = b.x; Bs[lk + 1][lr] = b.y; Bs[lk + 2][lr] = b.z; Bs[lk + 3][lr] = b.w;
    __syncthreads();
#pragma unroll
    for (int k = 0; k < 16; ++k) {
      const float4 av = *reinterpret_cast<const float4*>(&As[k][ty << 2]);
      const float4 bv = *reinterpret_cast<const float4*>(&Bs[k][tx << 2]);
      const float am[4] = {av.x, av.y, av.z, av.w};
      const float bb[4] = {bv.x, bv.y, bv.z, bv.w};
#pragma unroll
      for (int i = 0; i < 4; ++i)
#pragma unroll
        for (int j = 0; j < 4; ++j) acc[i][j] += am[i] * bb[j];
    }
    __syncthreads();
  }
  float4 badd = make_float4(0.f, 0.f, 0.f, 0.f);
  if (bias) badd = *reinterpret_cast<const float4*>(bias + bn + (tx << 2));
#pragma unroll
  for (int i = 0; i < 4; ++i) {
    const int m = bm + (ty << 2) + i;
    float4 r;
    r.x = acc[i][0] + badd.x; r.y = acc[i][1] + badd.y;
    r.z = acc[i][2] + badd.z; r.w = acc[i][3] + badd.w;
    *reinterpret_cast<float4*>(C + (size_t)m * N + bn + (tx << 2)) = r;
  }
}

// Fused q/k/v/g projection: grid.x selects weight (4 x D/64), grid.y = S/64.
__global__ __launch_bounds__(256)
void qkvg_kernel(const float* __restrict__ s, const float* __restrict__ Wq,
                 const float* __restrict__ bq, const float* __restrict__ Wk,
                 const float* __restrict__ Wv, const float* __restrict__ Wg,
                 float* __restrict__ out) {
  const int nb = D / 64;
  const int wsel = blockIdx.x / nb;
  const int bn = (blockIdx.x % nb) * 64;
  const int bm = blockIdx.y * 64;
  const float* W = (wsel == 0) ? Wq : (wsel == 1) ? Wk : (wsel == 2) ? Wv : Wg;
  const float* bias = (wsel == 0) ? bq : nullptr;
  float* C = out + (size_t)wsel * S * D;
  gemm_tile(s, nullptr, W, bias, C, bm, bn, D, D);
}

// Gated output projection: out = (o * sigmoid(g)) @ Wo^T
__global__ __launch_bounds__(256)
void outproj_kernel(const float* __restrict__ o, const float* __restrict__ g,
                    const float* __restrict__ Wo, float* __restrict__ out) {
  gemm_tile(o, g, Wo, nullptr, out, blockIdx.y * 64, blockIdx.x * 64, D, D);
}

// ---------------------------------------------------------------------------
// pair-bias prep: WzW[h][c] = Wz[h][c]*ln_w[c]; S1[h] = sum_c WzW; S2[h] =
// sum_c ln_b[c]*Wz[h][c].  One small block.
// ---------------------------------------------------------------------------
__global__ __launch_bounds__(256)
void pb_prep_kernel(const float* __restrict__ Wz, const float* __restrict__ ln_w,
                    const float* __restrict__ ln_b, float* __restrict__ wzw,
                    float* __restrict__ s12) {
  const int t = threadIdx.x;
  for (int e = t; e < 16 * DZ; e += 256) wzw[e] = Wz[e] * ln_w[e & 127];
  if (t < 32) {
    const int h = t & 15;
    const float* coef = (t < 16) ? ln_w : ln_b;
    float a = 0.f;
    for (int c = 0; c < DZ; ++c) a += Wz[h * DZ + c] * coef[c];
    s12[t] = a;
  }
}

// ---------------------------------------------------------------------------
// Pair bias v8 = v7 with the spill fixed: the ks slice loop is NOT unrolled
// (#pragma unroll 1). v6/v7 kept all 4 slices' loads in flight (32 float4 =
// 128 VGPRs) -> VGPR=256 + 3.1GB scratch spill traffic (measured). With
// unroll 1, in-flight = 8 float4; ~120 VGPR total, no spill.
// Structure: 2-D register tile (4 rows x 4 heads/lane), wave-autonomous
// 64-row chunk, [64][36] staging (b128 ops at the 8-phase floor), [16][132]
// broadcast weights, stride-17 epilogue transpose, coalesced h-plane writes.
// ---------------------------------------------------------------------------
__global__ __launch_bounds__(256)
void pair_bias_kernel(const float* __restrict__ z, const float* __restrict__ wzw,
                      const float* __restrict__ s12, float* __restrict__ bias_out) {
  __shared__ float wl[16 * 132];       // 8.25 KB padded weights
  __shared__ float s12l[32];
  __shared__ float zs[4][64 * 36];     // 9 KB per-wave staging (reused as T)
  __shared__ float mi[4][64][2];       // per-row (mu, inv)
  const int tid = threadIdx.x;
  const int lane = tid & 63;
  const int wv = tid >> 6;

  for (int e = tid; e < 16 * DZ; e += 256) wl[(e >> 7) * 132 + (e & 127)] = wzw[e];
  if (tid < 32) s12l[tid] = s12[tid];
  __syncthreads();   // only barrier

  float* Z = zs[wv];
  const int rg = lane >> 2, hg = lane & 3;      // compute roles
  const int lr8 = lane >> 3, lq = lane & 7;     // load roles
  const int chunk = blockIdx.x * 4 + wv;        // 16384 chunks of 64 rows
  const float* zc = z + (size_t)chunk * 64 * DZ;

  float acc[4][4] = {};
  float s1p[8] = {}, s2p[8] = {};

#pragma unroll 1   // CRITICAL: full unroll hoists 32 float4 loads -> spill
  for (int ks = 0; ks < 4; ++ks) {
    // load slice (8 coalesced dwordx4: 8 rows x 32 c per instr), stats, stage
#pragma unroll
    for (int j = 0; j < 8; ++j) {
      const float4 v = *reinterpret_cast<const float4*>(
          zc + (size_t)(j * 8 + lr8) * DZ + ks * 32 + lq * 4);
      s1p[j] += (v.x + v.y) + (v.z + v.w);
      s2p[j] = fmaf(v.x, v.x, fmaf(v.y, v.y, fmaf(v.z, v.z, fmaf(v.w, v.w, s2p[j]))));
      *reinterpret_cast<float4*>(&Z[(j * 8 + lr8) * 36 + lq * 4]) = v;
    }
    // compute 4x4 tile over this k-slice (rows rg+16i, heads hg*4+hj)
#pragma unroll
    for (int kq = 0; kq < 8; ++kq) {
      float4 zv[4], wvv[4];
#pragma unroll
      for (int i = 0; i < 4; ++i)
        zv[i] = *reinterpret_cast<const float4*>(&Z[(rg + 16 * i) * 36 + kq * 4]);
#pragma unroll
      for (int hj = 0; hj < 4; ++hj)
        wvv[hj] = *reinterpret_cast<const float4*>(&wl[(hg * 4 + hj) * 132 + ks * 32 + kq * 4]);
#pragma unroll
      for (int i = 0; i < 4; ++i)
#pragma unroll
        for (int hj = 0; hj < 4; ++hj)
          acc[i][hj] += zv[i].x * wvv[hj].x + zv[i].y * wvv[hj].y +
                        zv[i].z * wvv[hj].z + zv[i].w * wvv[hj].w;
    }
  }

  // finalize row stats (reduce over the 8 lanes sharing each row)
#pragma unroll
  for (int j = 0; j < 8; ++j) {
    float a = s1p[j], b = s2p[j];
    a += __shfl_xor(a, 1); b += __shfl_xor(b, 1);
    a += __shfl_xor(a, 2); b += __shfl_xor(b, 2);
    a += __shfl_xor(a, 4); b += __shfl_xor(b, 4);
    if (lq == 0) {
      const float mu = a * (1.f / DZ);
      mi[wv][j * 8 + lr8][0] = mu;
      mi[wv][j * 8 + lr8][1] = rsqrtf(b * (1.f / DZ) - mu * mu + EPS);
    }
  }

  // epilogue: affine + transpose through reused staging LDS (stride 17)
#pragma unroll
  for (int i = 0; i < 4; ++i) {
    const int r = rg + 16 * i;
    const float mu = mi[wv][r][0];
    const float iv = mi[wv][r][1];
#pragma unroll
    for (int hj = 0; hj < 4; ++hj) {
      const int h = hg * 4 + hj;
      Z[r * 17 + h] = iv * (acc[i][hj] - mu * s12l[h]) + s12l[16 + h];
    }
  }
  const size_t p0 = (size_t)chunk * 64;
#pragma unroll
  for (int hh = 0; hh < 16; ++hh)
    bias_out[(size_t)hh * S * S + p0 + lane] = Z[lane * 17 + hh];
}

// ---------------------------------------------------------------------------
// Flash-style attention. Block = (head h, 64 query rows), 256 threads (16x16).
// ---------------------------------------------------------------------------
__global__ __launch_bounds__(256)
void attn_kernel(const float* __restrict__ q_ws, const float* __restrict__ k_ws,
                 const float* __restrict__ v_ws, const float* __restrict__ bias,
                 float* __restrict__ o_ws) {
  __shared__ float Qs[64][52];   // query rows (scaled), padded
  __shared__ float Ks[64][52];   // key rows, padded
  __shared__ float Vt[48][68];   // V transposed [d][t]
  __shared__ float Ps[64][68];   // probabilities tile

  const int tid = threadIdx.x;
  const int tx = tid & 15, ty = tid >> 4;
  const int h  = blockIdx.x >> 4;
  const int q0 = (blockIdx.x & 15) << 6;
  const float scale = 0.14433756729740643f;  // 1/sqrt(48)

  // stage Q (scaled): 64 rows x 12 float4
#pragma unroll
  for (int i = 0; i < 3; ++i) {
    const int f4 = tid + i * 256;
    const int r = f4 / 12, c4 = f4 % 12;
    float4 v = *reinterpret_cast<const float4*>(q_ws + (size_t)(q0 + r) * D + h * HD + c4 * 4);
    v.x *= scale; v.y *= scale; v.z *= scale; v.w *= scale;
    *reinterpret_cast<float4*>(&Qs[r][c4 * 4]) = v;
  }

  float m[4], l[4] = {0.f, 0.f, 0.f, 0.f};
  float acc[4][3] = {};
#pragma unroll
  for (int i = 0; i < 4; ++i) m[i] = -1e30f;

  for (int t0 = 0; t0 < S; t0 += 64) {
    // stage K tile (rows) and V tile (transposed)
#pragma unroll
    for (int i = 0; i < 3; ++i) {
      const int f4 = tid + i * 256;
      const int r = f4 / 12, c4 = f4 % 12;
      const float4 kv = *reinterpret_cast<const float4*>(k_ws + (size_t)(t0 + r) * D + h * HD + c4 * 4);
      *reinterpret_cast<float4*>(&Ks[r][c4 * 4]) = kv;
      const float4 vv = *reinterpret_cast<const float4*>(v_ws + (size_t)(t0 + r) * D + h * HD + c4 * 4);
      Vt[c4 * 4 + 0][r] = vv.x; Vt[c4 * 4 + 1][r] = vv.y;
      Vt[c4 * 4 + 2][r] = vv.z; Vt[c4 * 4 + 3][r] = vv.w;
    }
    __syncthreads();

    // S-tile: rows 4ty+i, cols 4tx+j, init from bias
    float s4[4][4];
#pragma unroll
    for (int i = 0; i < 4; ++i) {
      const float4 b4 = *reinterpret_cast<const float4*>(
          bias + ((size_t)h * S + (q0 + 4 * ty + i)) * S + t0 + 4 * tx);
      s4[i][0] = b4.x; s4[i][1] = b4.y; s4[i][2] = b4.z; s4[i][3] = b4.w;
    }
#pragma unroll
    for (int k4 = 0; k4 < 12; ++k4) {
      float4 qv[4], kv[4];
#pragma unroll
      for (int i = 0; i < 4; ++i) qv[i] = *reinterpret_cast<const float4*>(&Qs[4 * ty + i][k4 * 4]);
#pragma unroll
      for (int j = 0; j < 4; ++j) kv[j] = *reinterpret_cast<const float4*>(&Ks[4 * tx + j][k4 * 4]);
#pragma unroll
      for (int i = 0; i < 4; ++i)
#pragma unroll
        for (int j = 0; j < 4; ++j)
          s4[i][j] += qv[i].x * kv[j].x + qv[i].y * kv[j].y +
                      qv[i].z * kv[j].z + qv[i].w * kv[j].w;
    }

    // online softmax (row groups = 16 tx lanes; shfl_xor stays in-group)
#pragma unroll
    for (int i = 0; i < 4; ++i) {
      float tmax = fmaxf(fmaxf(s4[i][0], s4[i][1]), fmaxf(s4[i][2], s4[i][3]));
#pragma unroll
      for (int off = 8; off >= 1; off >>= 1) tmax = fmaxf(tmax, __shfl_xor(tmax, off));
      const float mn = fmaxf(m[i], tmax);
      const float fac = __expf(m[i] - mn);
      float p0 = __expf(s4[i][0] - mn), p1 = __expf(s4[i][1] - mn);
      float p2 = __expf(s4[i][2] - mn), p3 = __expf(s4[i][3] - mn);
      l[i] = l[i] * fac + (p0 + p1 + p2 + p3);   // per-thread partial sum
      acc[i][0] *= fac; acc[i][1] *= fac; acc[i][2] *= fac;
      m[i] = mn;
      *reinterpret_cast<float4*>(&Ps[4 * ty + i][4 * tx]) = make_float4(p0, p1, p2, p3);
    }
    __syncthreads();

    // PV: rows 4ty+i, dims 3tx+j, vectorized over t-quads
#pragma unroll
    for (int t4 = 0; t4 < 16; ++t4) {
      float4 pv[4], vv[3];
#pragma unroll
      for (int i = 0; i < 4; ++i) pv[i] = *reinterpret_cast<const float4*>(&Ps[4 * ty + i][4 * t4]);
#pragma unroll
      for (int j = 0; j < 3; ++j) vv[j] = *reinterpret_cast<const float4*>(&Vt[3 * tx + j][4 * t4]);
#pragma unroll
      for (int i = 0; i < 4; ++i)
#pragma unroll
        for (int j = 0; j < 3; ++j)
          acc[i][j] += pv[i].x * vv[j].x + pv[i].y * vv[j].y +
                       pv[i].z * vv[j].z + pv[i].w * vv[j].w;
    }
    __syncthreads();
  }

  // finalize: full row sum of l across tx group, normalize, write
#pragma unroll
  for (int i = 0; i < 4; ++i) {
    float lt = l[i];
#pragma unroll
    for (int off = 8; off >= 1; off >>= 1) lt += __shfl_xor(lt, off);
    const float rl = 1.f / lt;
    float* op = o_ws + (size_t)(q0 + 4 * ty + i) * D + h * HD;
#pragma unroll
    for (int j = 0; j < 3; ++j) op[3 * tx + j] = acc[i][j] * rl;
  }
}

extern "C" void kernel_launch(void* const* d_in, const int* in_sizes, int n_in,
                              void* d_out, int out_size, void* d_ws, size_t ws_size,
                              hipStream_t stream) {
  const float* s    = (const float*)d_in[0];
  const float* z    = (const float*)d_in[1];
  const float* Wq   = (const float*)d_in[2];
  const float* bq   = (const float*)d_in[3];
  const float* Wk   = (const float*)d_in[4];
  const float* Wv   = (const float*)d_in[5];
  const float* Wg   = (const float*)d_in[6];
  const float* ln_w = (const float*)d_in[7];
  const float* ln_b = (const float*)d_in[8];
  const float* Wz   = (const float*)d_in[9];
  const float* Wo   = (const float*)d_in[10];
  float* out = (float*)d_out;

  // workspace (floats): q,k,v,g,o = 5*S*D; bias = H*S*S; wzw = 2048; s12 = 32
  float* q_ws    = (float*)d_ws;
  float* k_ws    = q_ws + (size_t)S * D;
  float* v_ws    = k_ws + (size_t)S * D;
  float* g_ws    = v_ws + (size_t)S * D;
  float* o_ws    = g_ws + (size_t)S * D;
  float* bias_ws = o_ws + (size_t)S * D;
  float* wzw_ws  = bias_ws + (size_t)H * S * S;
  float* s12_ws  = wzw_ws + 16 * DZ;

  // 1) fused QKVG projections
  qkvg_kernel<<<dim3(4 * (D / 64), S / 64), 256, 0, stream>>>(s, Wq, bq, Wk, Wv, Wg, q_ws);
  // 2) pair bias (LN folded): prep then streaming kernel
  pb_prep_kernel<<<1, 256, 0, stream>>>(Wz, ln_w, ln_b, wzw_ws, s12_ws);
  pair_bias_kernel<<<4096, 256, 0, stream>>>(z, wzw_ws, s12_ws, bias_ws);
  // 3) flash attention
  attn_kernel<<<dim3(H * (S / 64)), 256, 0, stream>>>(q_ws, k_ws, v_ws, bias_ws, o_ws);
  // 4) gate + output projection
  outproj_kernel<<<dim3(D / 64, S / 64), 256, 0, stream>>>(o_ws, g_ws, Wo, out);
}

// Round 10
// 418.233 us; speedup vs baseline: 4.5555x; 1.1789x over previous
//
#include <hip/hip_runtime.h>

constexpr int H  = 16;
constexpr int HD = 48;
constexpr int D  = 768;    // H*HD
constexpr int DZ = 128;
constexpr int S  = 1024;
constexpr float EPS = 1e-5f;

typedef __attribute__((ext_vector_type(8))) short bf16x8;
typedef __attribute__((ext_vector_type(4))) float f32x4;

__device__ __forceinline__ float sigmoidf_(float x) { return 1.f / (1.f + __expf(-x)); }

// f32 -> bf16 bits, round-to-nearest-even
__device__ __forceinline__ unsigned short f2b(float f) {
  unsigned u = __float_as_uint(f);
  u += 0x7FFFu + ((u >> 16) & 1u);
  return (unsigned short)(u >> 16);
}

// ---------------------------------------------------------------------------
// Tiled f32 GEMM body: C[m][n] = sum_k A[m][k] * W[n][k]  (+bias[n], A gated by
// sigmoid(G) if G != nullptr). BM=BN=64, BK=16, 256 threads, 4x4 micro-tile.
// ---------------------------------------------------------------------------
__device__ __forceinline__ void gemm_tile(const float* __restrict__ A,
                                          const float* __restrict__ G,
                                          const float* __restrict__ W,
                                          const float* __restrict__ bias,
                                          float* __restrict__ C,
                                          const int bm, const int bn,
                                          const int N, const int K) {
  __shared__ float As[16][68];   // [k][m], row stride 68 floats (16B-aligned rows)
  __shared__ float Bs[16][68];   // [k][n]
  const int tid = threadIdx.x;
  const int tx = tid & 15, ty = tid >> 4;
  const int lr = tid >> 2;          // 0..63 tile row
  const int lk = (tid & 3) << 2;    // 0,4,8,12
  float acc[4][4] = {};
  for (int k0 = 0; k0 < K; k0 += 16) {
    float4 a = *reinterpret_cast<const float4*>(A + (size_t)(bm + lr) * K + (k0 + lk));
    if (G) {
      const float4 g = *reinterpret_cast<const float4*>(G + (size_t)(bm + lr) * K + (k0 + lk));
      a.x *= sigmoidf_(g.x); a.y *= sigmoidf_(g.y);
      a.z *= sigmoidf_(g.z); a.w *= sigmoidf_(g.w);
    }
    const float4 b = *reinterpret_cast<const float4*>(W + (size_t)(bn + lr) * K + (k0 + lk));
    As[lk + 0][lr] = a.x; As[lk + 1][lr] = a.y; As[lk + 2][lr] = a.z; As[lk + 3][lr] = a.w;
    Bs[lk + 0][lr] = b.x; Bs[lk + 1][lr] = b.y; Bs[lk + 2][lr] = b.z; Bs[lk + 3][lr] = b.w;
    __syncthreads();
#pragma unroll
    for (int k = 0; k < 16; ++k) {
      const float4 av = *reinterpret_cast<const float4*>(&As[k][ty << 2]);
      const float4 bv = *reinterpret_cast<const float4*>(&Bs[k][tx << 2]);
      const float am[4] = {av.x, av.y, av.z, av.w};
      const float bb[4] = {bv.x, bv.y, bv.z, bv.w};
#pragma unroll
      for (int i = 0; i < 4; ++i)
#pragma unroll
        for (int j = 0; j < 4; ++j) acc[i][j] += am[i] * bb[j];
    }
    __syncthreads();
  }
  float4 badd = make_float4(0.f, 0.f, 0.f, 0.f);
  if (bias) badd = *reinterpret_cast<const float4*>(bias + bn + (tx << 2));
#pragma unroll
  for (int i = 0; i < 4; ++i) {
    const int m = bm + (ty << 2) + i;
    float4 r;
    r.x = acc[i][0] + badd.x; r.y = acc[i][1] + badd.y;
    r.z = acc[i][2] + badd.z; r.w = acc[i][3] + badd.w;
    *reinterpret_cast<float4*>(C + (size_t)m * N + bn + (tx << 2)) = r;
  }
}

// Fused q/k/v/g projection: grid.x selects weight (4 x D/64), grid.y = S/64.
__global__ __launch_bounds__(256)
void qkvg_kernel(const float* __restrict__ s, const float* __restrict__ Wq,
                 const float* __restrict__ bq, const float* __restrict__ Wk,
                 const float* __restrict__ Wv, const float* __restrict__ Wg,
                 float* __restrict__ out) {
  const int nb = D / 64;
  const int wsel = blockIdx.x / nb;
  const int bn = (blockIdx.x % nb) * 64;
  const int bm = blockIdx.y * 64;
  const float* W = (wsel == 0) ? Wq : (wsel == 1) ? Wk : (wsel == 2) ? Wv : Wg;
  const float* bias = (wsel == 0) ? bq : nullptr;
  float* C = out + (size_t)wsel * S * D;
  gemm_tile(s, nullptr, W, bias, C, bm, bn, D, D);
}

// Gated output projection: out = (o * sigmoid(g)) @ Wo^T
__global__ __launch_bounds__(256)
void outproj_kernel(const float* __restrict__ o, const float* __restrict__ g,
                    const float* __restrict__ Wo, float* __restrict__ out) {
  gemm_tile(o, g, Wo, nullptr, out, blockIdx.y * 64, blockIdx.x * 64, D, D);
}

// ---------------------------------------------------------------------------
// pair-bias prep: wzwb[h][c] = bf16(Wz[h][c]*ln_w[c]); S1[h] = sum_c of the
// ROUNDED bf16 weights (so the LN-fold identity matches the MFMA dot);
// S2[h] = sum_c ln_b[c]*Wz[h][c] (pure f32 term).
// ---------------------------------------------------------------------------
__global__ __launch_bounds__(256)
void pb_prep_kernel(const float* __restrict__ Wz, const float* __restrict__ ln_w,
                    const float* __restrict__ ln_b, unsigned short* __restrict__ wzwb,
                    float* __restrict__ s12) {
  const int t = threadIdx.x;
  for (int e = t; e < 16 * DZ; e += 256) wzwb[e] = f2b(Wz[e] * ln_w[e & 127]);
  __syncthreads();
  if (t < 32) {
    const int h = t & 15;
    float a = 0.f;
    if (t < 16) {
      for (int c = 0; c < DZ; ++c) {
        const unsigned u = (unsigned)wzwb[h * DZ + c] << 16;
        a += __uint_as_float(u);                 // sum of rounded weights
      }
    } else {
      for (int c = 0; c < DZ; ++c) a += Wz[h * DZ + c] * ln_b[c];
    }
    s12[t] = a;
  }
}

// ---------------------------------------------------------------------------
// Pair bias v9: MFMA. bias[:, st] tile = zn @ WzW^T done as bf16 MFMA GEMM
// [S^2 x 128] @ [128 x 16] with LN folded into the epilogue (linearity):
//   out[h][st] = inv[st]*(D[st][h] - mu[st]*S1[h]) + S2[h]
// One wave owns a 64-row chunk = 4 sub-tiles of 16 rows; per sub-tile:
//   A-frags loaded straight from global in fragment order (lane: row=l&15,
//   k=(l>>4)*8+j) -> 8 dwordx4/lane-group, 16 fully-consumed lines/instr;
//   f32 stats accumulated on the fly (exact LN), bf16 convert, 4 MFMAs.
//   Row stats reduced with 2 shfl_xor (lanes l^16, l^32). mu/inv moved to
//   D-layout lanes via __shfl. B-frags (bf16 weights) live in 16 VGPRs,
//   loaded once. LDS only for the 64x16 epilogue transpose (stride 17) ->
//   16 coalesced 256B h-plane writes. No barriers; ~8 waves/SIMD occupancy.
// ---------------------------------------------------------------------------
__global__ __launch_bounds__(256)
void pair_bias_kernel(const float* __restrict__ z, const unsigned short* __restrict__ wzwb,
                      const float* __restrict__ s12, float* __restrict__ bias_out) {
  __shared__ float T[4][64 * 17];      // 17.4 KB total, wave-private slabs
  const int tid = threadIdx.x;
  const int lane = tid & 63;
  const int wv = tid >> 6;
  const int hq = lane & 15;            // A row within sub-tile; B/D column (head)
  const int grp = lane >> 4;           // 0..3 (k-slice group / D row group)

  // B fragments: B[k = 32m + grp*8 + j][n = hq] = WzW_bf16[hq][k]
  bf16x8 bf[4];
#pragma unroll
  for (int m = 0; m < 4; ++m)
    bf[m] = *reinterpret_cast<const bf16x8*>(wzwb + hq * DZ + m * 32 + grp * 8);
  const float S1h = s12[hq], S2h = s12[16 + hq];

  const int chunk = blockIdx.x * 4 + wv;        // 16384 chunks of 64 rows
  const size_t p0 = (size_t)chunk * 64;
  float* Tw = &T[wv][0];

#pragma unroll 1   // keep one sub-tile of loads in flight (no spill)
  for (int sub = 0; sub < 4; ++sub) {
    const float* zr = z + (p0 + sub * 16 + hq) * DZ + grp * 8;
    f32x4 acc = {0.f, 0.f, 0.f, 0.f};
    float s1 = 0.f, s2 = 0.f;
#pragma unroll
    for (int m = 0; m < 4; ++m) {
      const float4 a0 = *reinterpret_cast<const float4*>(zr + m * 32);
      const float4 a1 = *reinterpret_cast<const float4*>(zr + m * 32 + 4);
      s1 += (a0.x + a0.y) + (a0.z + a0.w) + (a1.x + a1.y) + (a1.z + a1.w);
      s2 = fmaf(a0.x, a0.x, fmaf(a0.y, a0.y, fmaf(a0.z, a0.z, fmaf(a0.w, a0.w, s2))));
      s2 = fmaf(a1.x, a1.x, fmaf(a1.y, a1.y, fmaf(a1.z, a1.z, fmaf(a1.w, a1.w, s2))));
      bf16x8 af;
      af[0] = (short)f2b(a0.x); af[1] = (short)f2b(a0.y);
      af[2] = (short)f2b(a0.z); af[3] = (short)f2b(a0.w);
      af[4] = (short)f2b(a1.x); af[5] = (short)f2b(a1.y);
      af[6] = (short)f2b(a1.z); af[7] = (short)f2b(a1.w);
      acc = __builtin_amdgcn_mfma_f32_16x16x32_bf16(af, bf[m], acc, 0, 0, 0);
    }
    // full row stats for row (sub*16 + hq): combine the 4 k-slice groups
    s1 += __shfl_xor(s1, 16); s1 += __shfl_xor(s1, 32);
    s2 += __shfl_xor(s2, 16); s2 += __shfl_xor(s2, 32);
    const float mu = s1 * (1.f / DZ);
    const float inv = rsqrtf(s2 * (1.f / DZ) - mu * mu + EPS);
    // D layout: col = hq (head), rows st = grp*4 + r. Pull mu/inv of row st
    // from lane st (which owns row st's stats).
#pragma unroll
    for (int r = 0; r < 4; ++r) {
      const int st = grp * 4 + r;
      const float mur = __shfl(mu, st);
      const float invr = __shfl(inv, st);
      Tw[(sub * 16 + st) * 17 + hq] = invr * (acc[r] - mur * S1h) + S2h;
    }
  }
  // coalesced h-plane writes: 64 consecutive floats per plane
#pragma unroll
  for (int hh = 0; hh < 16; ++hh)
    bias_out[(size_t)hh * S * S + p0 + lane] = Tw[lane * 17 + hh];
}

// ---------------------------------------------------------------------------
// Flash-style attention. Block = (head h, 64 query rows), 256 threads (16x16).
// ---------------------------------------------------------------------------
__global__ __launch_bounds__(256)
void attn_kernel(const float* __restrict__ q_ws, const float* __restrict__ k_ws,
                 const float* __restrict__ v_ws, const float* __restrict__ bias,
                 float* __restrict__ o_ws) {
  __shared__ float Qs[64][52];   // query rows (scaled), padded
  __shared__ float Ks[64][52];   // key rows, padded
  __shared__ float Vt[48][68];   // V transposed [d][t]
  __shared__ float Ps[64][68];   // probabilities tile

  const int tid = threadIdx.x;
  const int tx = tid & 15, ty = tid >> 4;
  const int h  = blockIdx.x >> 4;
  const int q0 = (blockIdx.x & 15) << 6;
  const float scale = 0.14433756729740643f;  // 1/sqrt(48)

  // stage Q (scaled): 64 rows x 12 float4
#pragma unroll
  for (int i = 0; i < 3; ++i) {
    const int f4 = tid + i * 256;
    const int r = f4 / 12, c4 = f4 % 12;
    float4 v = *reinterpret_cast<const float4*>(q_ws + (size_t)(q0 + r) * D + h * HD + c4 * 4);
    v.x *= scale; v.y *= scale; v.z *= scale; v.w *= scale;
    *reinterpret_cast<float4*>(&Qs[r][c4 * 4]) = v;
  }

  float m[4], l[4] = {0.f, 0.f, 0.f, 0.f};
  float acc[4][3] = {};
#pragma unroll
  for (int i = 0; i < 4; ++i) m[i] = -1e30f;

  for (int t0 = 0; t0 < S; t0 += 64) {
    // stage K tile (rows) and V tile (transposed)
#pragma unroll
    for (int i = 0; i < 3; ++i) {
      const int f4 = tid + i * 256;
      const int r = f4 / 12, c4 = f4 % 12;
      const float4 kv = *reinterpret_cast<const float4*>(k_ws + (size_t)(t0 + r) * D + h * HD + c4 * 4);
      *reinterpret_cast<float4*>(&Ks[r][c4 * 4]) = kv;
      const float4 vv = *reinterpret_cast<const float4*>(v_ws + (size_t)(t0 + r) * D + h * HD + c4 * 4);
      Vt[c4 * 4 + 0][r] = vv.x; Vt[c4 * 4 + 1][r] = vv.y;
      Vt[c4 * 4 + 2][r] = vv.z; Vt[c4 * 4 + 3][r] = vv.w;
    }
    __syncthreads();

    // S-tile: rows 4ty+i, cols 4tx+j, init from bias
    float s4[4][4];
#pragma unroll
    for (int i = 0; i < 4; ++i) {
      const float4 b4 = *reinterpret_cast<const float4*>(
          bias + ((size_t)h * S + (q0 + 4 * ty + i)) * S + t0 + 4 * tx);
      s4[i][0] = b4.x; s4[i][1] = b4.y; s4[i][2] = b4.z; s4[i][3] = b4.w;
    }
#pragma unroll
    for (int k4 = 0; k4 < 12; ++k4) {
      float4 qv[4], kv[4];
#pragma unroll
      for (int i = 0; i < 4; ++i) qv[i] = *reinterpret_cast<const float4*>(&Qs[4 * ty + i][k4 * 4]);
#pragma unroll
      for (int j = 0; j < 4; ++j) kv[j] = *reinterpret_cast<const float4*>(&Ks[4 * tx + j][k4 * 4]);
#pragma unroll
      for (int i = 0; i < 4; ++i)
#pragma unroll
        for (int j = 0; j < 4; ++j)
          s4[i][j] += qv[i].x * kv[j].x + qv[i].y * kv[j].y +
                      qv[i].z * kv[j].z + qv[i].w * kv[j].w;
    }

    // online softmax (row groups = 16 tx lanes; shfl_xor stays in-group)
#pragma unroll
    for (int i = 0; i < 4; ++i) {
      float tmax = fmaxf(fmaxf(s4[i][0], s4[i][1]), fmaxf(s4[i][2], s4[i][3]));
#pragma unroll
      for (int off = 8; off >= 1; off >>= 1) tmax = fmaxf(tmax, __shfl_xor(tmax, off));
      const float mn = fmaxf(m[i], tmax);
      const float fac = __expf(m[i] - mn);
      float p0 = __expf(s4[i][0] - mn), p1 = __expf(s4[i][1] - mn);
      float p2 = __expf(s4[i][2] - mn), p3 = __expf(s4[i][3] - mn);
      l[i] = l[i] * fac + (p0 + p1 + p2 + p3);   // per-thread partial sum
      acc[i][0] *= fac; acc[i][1] *= fac; acc[i][2] *= fac;
      m[i] = mn;
      *reinterpret_cast<float4*>(&Ps[4 * ty + i][4 * tx]) = make_float4(p0, p1, p2, p3);
    }
    __syncthreads();

    // PV: rows 4ty+i, dims 3tx+j, vectorized over t-quads
#pragma unroll
    for (int t4 = 0; t4 < 16; ++t4) {
      float4 pv[4], vv[3];
#pragma unroll
      for (int i = 0; i < 4; ++i) pv[i] = *reinterpret_cast<const float4*>(&Ps[4 * ty + i][4 * t4]);
#pragma unroll
      for (int j = 0; j < 3; ++j) vv[j] = *reinterpret_cast<const float4*>(&Vt[3 * tx + j][4 * t4]);
#pragma unroll
      for (int i = 0; i < 4; ++i)
#pragma unroll
        for (int j = 0; j < 3; ++j)
          acc[i][j] += pv[i].x * vv[j].x + pv[i].y * vv[j].y +
                       pv[i].z * vv[j].z + pv[i].w * vv[j].w;
    }
    __syncthreads();
  }

  // finalize: full row sum of l across tx group, normalize, write
#pragma unroll
  for (int i = 0; i < 4; ++i) {
    float lt = l[i];
#pragma unroll
    for (int off = 8; off >= 1; off >>= 1) lt += __shfl_xor(lt, off);
    const float rl = 1.f / lt;
    float* op = o_ws + (size_t)(q0 + 4 * ty + i) * D + h * HD;
#pragma unroll
    for (int j = 0; j < 3; ++j) op[3 * tx + j] = acc[i][j] * rl;
  }
}

extern "C" void kernel_launch(void* const* d_in, const int* in_sizes, int n_in,
                              void* d_out, int out_size, void* d_ws, size_t ws_size,
                              hipStream_t stream) {
  const float* s    = (const float*)d_in[0];
  const float* z    = (const float*)d_in[1];
  const float* Wq   = (const float*)d_in[2];
  const float* bq   = (const float*)d_in[3];
  const float* Wk   = (const float*)d_in[4];
  const float* Wv   = (const float*)d_in[5];
  const float* Wg   = (const float*)d_in[6];
  const float* ln_w = (const float*)d_in[7];
  const float* ln_b = (const float*)d_in[8];
  const float* Wz   = (const float*)d_in[9];
  const float* Wo   = (const float*)d_in[10];
  float* out = (float*)d_out;

  // workspace (floats): q,k,v,g,o = 5*S*D; bias = H*S*S; wzwb (2048 ushort
  // in 1024-float slot, padded to 2048 floats for alignment); s12 = 32
  float* q_ws    = (float*)d_ws;
  float* k_ws    = q_ws + (size_t)S * D;
  float* v_ws    = k_ws + (size_t)S * D;
  float* g_ws    = v_ws + (size_t)S * D;
  float* o_ws    = g_ws + (size_t)S * D;
  float* bias_ws = o_ws + (size_t)S * D;
  unsigned short* wzwb_ws = (unsigned short*)(bias_ws + (size_t)H * S * S);
  float* s12_ws  = bias_ws + (size_t)H * S * S + 2048;

  // 1) fused QKVG projections
  qkvg_kernel<<<dim3(4 * (D / 64), S / 64), 256, 0, stream>>>(s, Wq, bq, Wk, Wv, Wg, q_ws);
  // 2) pair bias (LN folded): prep then MFMA streaming kernel
  pb_prep_kernel<<<1, 256, 0, stream>>>(Wz, ln_w, ln_b, wzwb_ws, s12_ws);
  pair_bias_kernel<<<4096, 256, 0, stream>>>(z, wzwb_ws, s12_ws, bias_ws);
  // 3) flash attention
  attn_kernel<<<dim3(H * (S / 64)), 256, 0, stream>>>(q_ws, k_ws, v_ws, bias_ws, o_ws);
  // 4) gate + output projection
  outproj_kernel<<<dim3(D / 64, S / 64), 256, 0, stream>>>(o_ws, g_ws, Wo, out);
}

// Round 11
// 387.777 us; speedup vs baseline: 4.9133x; 1.0785x over previous
//
#include <hip/hip_runtime.h>

constexpr int H  = 16;
constexpr int HD = 48;
constexpr int D  = 768;    // H*HD
constexpr int DZ = 128;
constexpr int S  = 1024;
constexpr float EPS = 1e-5f;

typedef __attribute__((ext_vector_type(8))) short bf16x8;
typedef __attribute__((ext_vector_type(4))) float f32x4;

__device__ __forceinline__ float sigmoidf_(float x) { return 1.f / (1.f + __expf(-x)); }

// f32 -> bf16 bits, round-to-nearest-even
__device__ __forceinline__ unsigned short f2b(float f) {
  unsigned u = __float_as_uint(f);
  u += 0x7FFFu + ((u >> 16) & 1u);
  return (unsigned short)(u >> 16);
}
// split x = hi + lo (both bf16); x - bf16(x) is exact (Sterbenz), residual ~2^-17
__device__ __forceinline__ void split2(float x, unsigned short& h, unsigned short& l) {
  const unsigned short hb = f2b(x);
  const float hf = __uint_as_float((unsigned)hb << 16);
  h = hb;
  l = f2b(x - hf);
}

// ---------------------------------------------------------------------------
// split6: s (S*D) and the 5 weight matrices (D*D each: Wq,Wk,Wv,Wg,Wo) ->
// bf16 hi/lo pairs. blockIdx.y selects the segment.
// ---------------------------------------------------------------------------
__global__ __launch_bounds__(256)
void split6_kernel(const float* __restrict__ s, const float* __restrict__ Wq,
                   const float* __restrict__ Wk, const float* __restrict__ Wv,
                   const float* __restrict__ Wg, const float* __restrict__ Wo,
                   unsigned short* __restrict__ s_hi, unsigned short* __restrict__ s_lo,
                   unsigned short* __restrict__ w_hi, unsigned short* __restrict__ w_lo) {
  const int seg = blockIdx.y;
  const float* src;
  unsigned short *dh, *dl;
  int n;
  if (seg == 0) { src = s; dh = s_hi; dl = s_lo; n = S * D; }
  else {
    src = (seg == 1) ? Wq : (seg == 2) ? Wk : (seg == 3) ? Wv : (seg == 4) ? Wg : Wo;
    dh = w_hi + (size_t)(seg - 1) * D * D;
    dl = w_lo + (size_t)(seg - 1) * D * D;
    n = D * D;
  }
  const int i4 = blockIdx.x * 256 + threadIdx.x;
  if (i4 * 4 < n) {
    const float4 v = *reinterpret_cast<const float4*>(src + (size_t)i4 * 4);
    ushort4 hh, ll;
    split2(v.x, hh.x, ll.x); split2(v.y, hh.y, ll.y);
    split2(v.z, hh.z, ll.z); split2(v.w, hh.w, ll.w);
    *reinterpret_cast<ushort4*>(dh + (size_t)i4 * 4) = hh;
    *reinterpret_cast<ushort4*>(dl + (size_t)i4 * 4) = ll;
  }
}

// gated activation split: a = o * sigmoid(g) -> a_hi, a_lo
__global__ __launch_bounds__(256)
void og_split_kernel(const float* __restrict__ o, const float* __restrict__ g,
                     unsigned short* __restrict__ a_hi, unsigned short* __restrict__ a_lo) {
  const int i4 = blockIdx.x * 256 + threadIdx.x;
  if (i4 * 4 >= S * D) return;
  const float4 ov = *reinterpret_cast<const float4*>(o + (size_t)i4 * 4);
  const float4 gv = *reinterpret_cast<const float4*>(g + (size_t)i4 * 4);
  ushort4 hh, ll;
  split2(ov.x * sigmoidf_(gv.x), hh.x, ll.x);
  split2(ov.y * sigmoidf_(gv.y), hh.y, ll.y);
  split2(ov.z * sigmoidf_(gv.z), hh.z, ll.z);
  split2(ov.w * sigmoidf_(gv.w), hh.w, ll.w);
  *reinterpret_cast<ushort4*>(a_hi + (size_t)i4 * 4) = hh;
  *reinterpret_cast<ushort4*>(a_lo + (size_t)i4 * 4) = ll;
}

// ---------------------------------------------------------------------------
// Split-bf16 MFMA GEMM: one wave computes a 32x32 tile of C = A @ W^T.
// A[m][k] (S x D), W[n][k] (D x D), both as hi/lo bf16 planes.
// Fragment order (validated by pair_bias v9): lane l -> row = l&15,
// k = (l>>4)*8+j; D: col = l&15, row = (l>>4)*4+r.
// x*w = hi*hi + hi*lo + lo*hi (lo*lo ~2^-17 rel, dropped): 3 MFMA into 1 acc.
// No LDS anywhere; operands are L2-resident.
// ---------------------------------------------------------------------------
__device__ __forceinline__ void mfma_tile32(const unsigned short* __restrict__ Ah,
                                            const unsigned short* __restrict__ Al,
                                            const unsigned short* __restrict__ Wh,
                                            const unsigned short* __restrict__ Wl,
                                            const float* __restrict__ bias,
                                            float* __restrict__ C,
                                            const int m0, const int n0) {
  const int lane = threadIdx.x & 63;
  const int r16 = lane & 15, kg = lane >> 4;
  const unsigned short* pah = Ah + (size_t)(m0 + r16) * D + kg * 8;
  const unsigned short* pal = Al + (size_t)(m0 + r16) * D + kg * 8;
  const unsigned short* pbh = Wh + (size_t)(n0 + r16) * D + kg * 8;
  const unsigned short* pbl = Wl + (size_t)(n0 + r16) * D + kg * 8;

  f32x4 a00 = {0.f, 0.f, 0.f, 0.f}, a01 = a00, a10 = a00, a11 = a00;
#pragma unroll 2   // bounded in-flight loads (full unroll would hoist->spill)
  for (int k = 0; k < D; k += 32) {
    const bf16x8 ah0 = *reinterpret_cast<const bf16x8*>(pah + k);
    const bf16x8 ah1 = *reinterpret_cast<const bf16x8*>(pah + 16 * D + k);
    const bf16x8 al0 = *reinterpret_cast<const bf16x8*>(pal + k);
    const bf16x8 al1 = *reinterpret_cast<const bf16x8*>(pal + 16 * D + k);
    const bf16x8 bh0 = *reinterpret_cast<const bf16x8*>(pbh + k);
    const bf16x8 bh1 = *reinterpret_cast<const bf16x8*>(pbh + 16 * D + k);
    const bf16x8 bl0 = *reinterpret_cast<const bf16x8*>(pbl + k);
    const bf16x8 bl1 = *reinterpret_cast<const bf16x8*>(pbl + 16 * D + k);
    a00 = __builtin_amdgcn_mfma_f32_16x16x32_bf16(ah0, bh0, a00, 0, 0, 0);
    a00 = __builtin_amdgcn_mfma_f32_16x16x32_bf16(ah0, bl0, a00, 0, 0, 0);
    a00 = __builtin_amdgcn_mfma_f32_16x16x32_bf16(al0, bh0, a00, 0, 0, 0);
    a01 = __builtin_amdgcn_mfma_f32_16x16x32_bf16(ah0, bh1, a01, 0, 0, 0);
    a01 = __builtin_amdgcn_mfma_f32_16x16x32_bf16(ah0, bl1, a01, 0, 0, 0);
    a01 = __builtin_amdgcn_mfma_f32_16x16x32_bf16(al0, bh1, a01, 0, 0, 0);
    a10 = __builtin_amdgcn_mfma_f32_16x16x32_bf16(ah1, bh0, a10, 0, 0, 0);
    a10 = __builtin_amdgcn_mfma_f32_16x16x32_bf16(ah1, bl0, a10, 0, 0, 0);
    a10 = __builtin_amdgcn_mfma_f32_16x16x32_bf16(al1, bh0, a10, 0, 0, 0);
    a11 = __builtin_amdgcn_mfma_f32_16x16x32_bf16(ah1, bh1, a11, 0, 0, 0);
    a11 = __builtin_amdgcn_mfma_f32_16x16x32_bf16(ah1, bl1, a11, 0, 0, 0);
    a11 = __builtin_amdgcn_mfma_f32_16x16x32_bf16(al1, bh1, a11, 0, 0, 0);
  }
  const float b0 = bias ? bias[n0 + r16] : 0.f;
  const float b1 = bias ? bias[n0 + 16 + r16] : 0.f;
#pragma unroll
  for (int r = 0; r < 4; ++r) {
    const int row0 = m0 + kg * 4 + r;
    C[(size_t)row0 * D + n0 + r16] = a00[r] + b0;
    C[(size_t)row0 * D + n0 + 16 + r16] = a01[r] + b1;
    C[(size_t)(row0 + 16) * D + n0 + r16] = a10[r] + b0;
    C[(size_t)(row0 + 16) * D + n0 + 16 + r16] = a11[r] + b1;
  }
}

// qkvg: 4 weights x (1024/32) x (768/32) = 3072 waves = 768 blocks
__global__ __launch_bounds__(256)
void qkvg_mfma_kernel(const unsigned short* __restrict__ s_hi,
                      const unsigned short* __restrict__ s_lo,
                      const unsigned short* __restrict__ w_hi,
                      const unsigned short* __restrict__ w_lo,
                      const float* __restrict__ bq, float* __restrict__ out) {
  const int wid = blockIdx.x * 4 + (threadIdx.x >> 6);
  const int wsel = wid / 768;
  const int r = wid % 768;
  const int m0 = (r / 24) * 32, n0 = (r % 24) * 32;
  mfma_tile32(s_hi, s_lo, w_hi + (size_t)wsel * D * D, w_lo + (size_t)wsel * D * D,
              (wsel == 0) ? bq : nullptr, out + (size_t)wsel * S * D, m0, n0);
}

// outproj: 768 waves = 192 blocks; weight index 4 (Wo); A = gated o
__global__ __launch_bounds__(256)
void outproj_mfma_kernel(const unsigned short* __restrict__ a_hi,
                         const unsigned short* __restrict__ a_lo,
                         const unsigned short* __restrict__ w_hi,
                         const unsigned short* __restrict__ w_lo,
                         float* __restrict__ out) {
  const int wid = blockIdx.x * 4 + (threadIdx.x >> 6);
  const int m0 = (wid / 24) * 32, n0 = (wid % 24) * 32;
  mfma_tile32(a_hi, a_lo, w_hi + (size_t)4 * D * D, w_lo + (size_t)4 * D * D,
              nullptr, out, m0, n0);
}

// ---------------------------------------------------------------------------
// pair-bias prep: wzwb[h][c] = bf16(Wz[h][c]*ln_w[c]); S1[h] = sum of ROUNDED
// bf16 weights (matches the MFMA dot); S2[h] = sum_c ln_b[c]*Wz[h][c].
// ---------------------------------------------------------------------------
__global__ __launch_bounds__(256)
void pb_prep_kernel(const float* __restrict__ Wz, const float* __restrict__ ln_w,
                    const float* __restrict__ ln_b, unsigned short* __restrict__ wzwb,
                    float* __restrict__ s12) {
  const int t = threadIdx.x;
  for (int e = t; e < 16 * DZ; e += 256) wzwb[e] = f2b(Wz[e] * ln_w[e & 127]);
  __syncthreads();
  if (t < 32) {
    const int h = t & 15;
    float a = 0.f;
    if (t < 16) {
      for (int c = 0; c < DZ; ++c) {
        const unsigned u = (unsigned)wzwb[h * DZ + c] << 16;
        a += __uint_as_float(u);
      }
    } else {
      for (int c = 0; c < DZ; ++c) a += Wz[h * DZ + c] * ln_b[c];
    }
    s12[t] = a;
  }
}

// ---------------------------------------------------------------------------
// Pair bias v9 (MFMA, LN folded into epilogue) — unchanged from round 10.
// ---------------------------------------------------------------------------
__global__ __launch_bounds__(256)
void pair_bias_kernel(const float* __restrict__ z, const unsigned short* __restrict__ wzwb,
                      const float* __restrict__ s12, float* __restrict__ bias_out) {
  __shared__ float T[4][64 * 17];
  const int tid = threadIdx.x;
  const int lane = tid & 63;
  const int wv = tid >> 6;
  const int hq = lane & 15;
  const int grp = lane >> 4;

  bf16x8 bf[4];
#pragma unroll
  for (int m = 0; m < 4; ++m)
    bf[m] = *reinterpret_cast<const bf16x8*>(wzwb + hq * DZ + m * 32 + grp * 8);
  const float S1h = s12[hq], S2h = s12[16 + hq];

  const int chunk = blockIdx.x * 4 + wv;
  const size_t p0 = (size_t)chunk * 64;
  float* Tw = &T[wv][0];

#pragma unroll 1
  for (int sub = 0; sub < 4; ++sub) {
    const float* zr = z + (p0 + sub * 16 + hq) * DZ + grp * 8;
    f32x4 acc = {0.f, 0.f, 0.f, 0.f};
    float s1 = 0.f, s2 = 0.f;
#pragma unroll
    for (int m = 0; m < 4; ++m) {
      const float4 a0 = *reinterpret_cast<const float4*>(zr + m * 32);
      const float4 a1 = *reinterpret_cast<const float4*>(zr + m * 32 + 4);
      s1 += (a0.x + a0.y) + (a0.z + a0.w) + (a1.x + a1.y) + (a1.z + a1.w);
      s2 = fmaf(a0.x, a0.x, fmaf(a0.y, a0.y, fmaf(a0.z, a0.z, fmaf(a0.w, a0.w, s2))));
      s2 = fmaf(a1.x, a1.x, fmaf(a1.y, a1.y, fmaf(a1.z, a1.z, fmaf(a1.w, a1.w, s2))));
      bf16x8 af;
      af[0] = (short)f2b(a0.x); af[1] = (short)f2b(a0.y);
      af[2] = (short)f2b(a0.z); af[3] = (short)f2b(a0.w);
      af[4] = (short)f2b(a1.x); af[5] = (short)f2b(a1.y);
      af[6] = (short)f2b(a1.z); af[7] = (short)f2b(a1.w);
      acc = __builtin_amdgcn_mfma_f32_16x16x32_bf16(af, bf[m], acc, 0, 0, 0);
    }
    s1 += __shfl_xor(s1, 16); s1 += __shfl_xor(s1, 32);
    s2 += __shfl_xor(s2, 16); s2 += __shfl_xor(s2, 32);
    const float mu = s1 * (1.f / DZ);
    const float inv = rsqrtf(s2 * (1.f / DZ) - mu * mu + EPS);
#pragma unroll
    for (int r = 0; r < 4; ++r) {
      const int st = grp * 4 + r;
      const float mur = __shfl(mu, st);
      const float invr = __shfl(inv, st);
      Tw[(sub * 16 + st) * 17 + hq] = invr * (acc[r] - mur * S1h) + S2h;
    }
  }
#pragma unroll
  for (int hh = 0; hh < 16; ++hh)
    bias_out[(size_t)hh * S * S + p0 + lane] = Tw[lane * 17 + hh];
}

// ---------------------------------------------------------------------------
// Flash-style attention. Block = (head h, 64 query rows), 256 threads (16x16).
// ---------------------------------------------------------------------------
__global__ __launch_bounds__(256)
void attn_kernel(const float* __restrict__ q_ws, const float* __restrict__ k_ws,
                 const float* __restrict__ v_ws, const float* __restrict__ bias,
                 float* __restrict__ o_ws) {
  __shared__ float Qs[64][52];   // query rows (scaled), padded
  __shared__ float Ks[64][52];   // key rows, padded
  __shared__ float Vt[48][68];   // V transposed [d][t]
  __shared__ float Ps[64][68];   // probabilities tile

  const int tid = threadIdx.x;
  const int tx = tid & 15, ty = tid >> 4;
  const int h  = blockIdx.x >> 4;
  const int q0 = (blockIdx.x & 15) << 6;
  const float scale = 0.14433756729740643f;  // 1/sqrt(48)

#pragma unroll
  for (int i = 0; i < 3; ++i) {
    const int f4 = tid + i * 256;
    const int r = f4 / 12, c4 = f4 % 12;
    float4 v = *reinterpret_cast<const float4*>(q_ws + (size_t)(q0 + r) * D + h * HD + c4 * 4);
    v.x *= scale; v.y *= scale; v.z *= scale; v.w *= scale;
    *reinterpret_cast<float4*>(&Qs[r][c4 * 4]) = v;
  }

  float m[4], l[4] = {0.f, 0.f, 0.f, 0.f};
  float acc[4][3] = {};
#pragma unroll
  for (int i = 0; i < 4; ++i) m[i] = -1e30f;

  for (int t0 = 0; t0 < S; t0 += 64) {
#pragma unroll
    for (int i = 0; i < 3; ++i) {
      const int f4 = tid + i * 256;
      const int r = f4 / 12, c4 = f4 % 12;
      const float4 kv = *reinterpret_cast<const float4*>(k_ws + (size_t)(t0 + r) * D + h * HD + c4 * 4);
      *reinterpret_cast<float4*>(&Ks[r][c4 * 4]) = kv;
      const float4 vv = *reinterpret_cast<const float4*>(v_ws + (size_t)(t0 + r) * D + h * HD + c4 * 4);
      Vt[c4 * 4 + 0][r] = vv.x; Vt[c4 * 4 + 1][r] = vv.y;
      Vt[c4 * 4 + 2][r] = vv.z; Vt[c4 * 4 + 3][r] = vv.w;
    }
    __syncthreads();

    float s4[4][4];
#pragma unroll
    for (int i = 0; i < 4; ++i) {
      const float4 b4 = *reinterpret_cast<const float4*>(
          bias + ((size_t)h * S + (q0 + 4 * ty + i)) * S + t0 + 4 * tx);
      s4[i][0] = b4.x; s4[i][1] = b4.y; s4[i][2] = b4.z; s4[i][3] = b4.w;
    }
#pragma unroll
    for (int k4 = 0; k4 < 12; ++k4) {
      float4 qv[4], kv[4];
#pragma unroll
      for (int i = 0; i < 4; ++i) qv[i] = *reinterpret_cast<const float4*>(&Qs[4 * ty + i][k4 * 4]);
#pragma unroll
      for (int j = 0; j < 4; ++j) kv[j] = *reinterpret_cast<const float4*>(&Ks[4 * tx + j][k4 * 4]);
#pragma unroll
      for (int i = 0; i < 4; ++i)
#pragma unroll
        for (int j = 0; j < 4; ++j)
          s4[i][j] += qv[i].x * kv[j].x + qv[i].y * kv[j].y +
                      qv[i].z * kv[j].z + qv[i].w * kv[j].w;
    }

#pragma unroll
    for (int i = 0; i < 4; ++i) {
      float tmax = fmaxf(fmaxf(s4[i][0], s4[i][1]), fmaxf(s4[i][2], s4[i][3]));
#pragma unroll
      for (int off = 8; off >= 1; off >>= 1) tmax = fmaxf(tmax, __shfl_xor(tmax, off));
      const float mn = fmaxf(m[i], tmax);
      const float fac = __expf(m[i] - mn);
      float p0 = __expf(s4[i][0] - mn), p1 = __expf(s4[i][1] - mn);
      float p2 = __expf(s4[i][2] - mn), p3 = __expf(s4[i][3] - mn);
      l[i] = l[i] * fac + (p0 + p1 + p2 + p3);
      acc[i][0] *= fac; acc[i][1] *= fac; acc[i][2] *= fac;
      m[i] = mn;
      *reinterpret_cast<float4*>(&Ps[4 * ty + i][4 * tx]) = make_float4(p0, p1, p2, p3);
    }
    __syncthreads();

#pragma unroll
    for (int t4 = 0; t4 < 16; ++t4) {
      float4 pv[4], vv[3];
#pragma unroll
      for (int i = 0; i < 4; ++i) pv[i] = *reinterpret_cast<const float4*>(&Ps[4 * ty + i][4 * t4]);
#pragma unroll
      for (int j = 0; j < 3; ++j) vv[j] = *reinterpret_cast<const float4*>(&Vt[3 * tx + j][4 * t4]);
#pragma unroll
      for (int i = 0; i < 4; ++i)
#pragma unroll
        for (int j = 0; j < 3; ++j)
          acc[i][j] += pv[i].x * vv[j].x + pv[i].y * vv[j].y +
                       pv[i].z * vv[j].z + pv[i].w * vv[j].w;
    }
    __syncthreads();
  }

#pragma unroll
  for (int i = 0; i < 4; ++i) {
    float lt = l[i];
#pragma unroll
    for (int off = 8; off >= 1; off >>= 1) lt += __shfl_xor(lt, off);
    const float rl = 1.f / lt;
    float* op = o_ws + (size_t)(q0 + 4 * ty + i) * D + h * HD;
#pragma unroll
    for (int j = 0; j < 3; ++j) op[3 * tx + j] = acc[i][j] * rl;
  }
}

extern "C" void kernel_launch(void* const* d_in, const int* in_sizes, int n_in,
                              void* d_out, int out_size, void* d_ws, size_t ws_size,
                              hipStream_t stream) {
  const float* s    = (const float*)d_in[0];
  const float* z    = (const float*)d_in[1];
  const float* Wq   = (const float*)d_in[2];
  const float* bq   = (const float*)d_in[3];
  const float* Wk   = (const float*)d_in[4];
  const float* Wv   = (const float*)d_in[5];
  const float* Wg   = (const float*)d_in[6];
  const float* ln_w = (const float*)d_in[7];
  const float* ln_b = (const float*)d_in[8];
  const float* Wz   = (const float*)d_in[9];
  const float* Wo   = (const float*)d_in[10];
  float* out = (float*)d_out;

  // workspace (floats): q,k,v,g,o = 5*S*D; bias = H*S*S; wzwb+pad; s12;
  // then bf16 area: s_hi/lo, w_hi/lo (5 mats), a_hi/lo
  float* q_ws    = (float*)d_ws;
  float* k_ws    = q_ws + (size_t)S * D;
  float* v_ws    = k_ws + (size_t)S * D;
  float* g_ws    = v_ws + (size_t)S * D;
  float* o_ws    = g_ws + (size_t)S * D;
  float* bias_ws = o_ws + (size_t)S * D;
  unsigned short* wzwb_ws = (unsigned short*)(bias_ws + (size_t)H * S * S);
  float* s12_ws  = bias_ws + (size_t)H * S * S + 2048;
  unsigned short* s_hi = (unsigned short*)(s12_ws + 32);
  unsigned short* s_lo = s_hi + (size_t)S * D;
  unsigned short* w_hi = s_lo + (size_t)S * D;
  unsigned short* w_lo = w_hi + (size_t)5 * D * D;
  unsigned short* a_hi = w_lo + (size_t)5 * D * D;
  unsigned short* a_lo = a_hi + (size_t)S * D;

  // 0) split s + weights into bf16 hi/lo planes
  split6_kernel<<<dim3((S * D / 4 + 255) / 256, 6), 256, 0, stream>>>(
      s, Wq, Wk, Wv, Wg, Wo, s_hi, s_lo, w_hi, w_lo);
  // 1) fused QKVG projections (split-bf16 MFMA)
  qkvg_mfma_kernel<<<768, 256, 0, stream>>>(s_hi, s_lo, w_hi, w_lo, bq, q_ws);
  // 2) pair bias (LN folded): prep then MFMA streaming kernel
  pb_prep_kernel<<<1, 256, 0, stream>>>(Wz, ln_w, ln_b, wzwb_ws, s12_ws);
  pair_bias_kernel<<<4096, 256, 0, stream>>>(z, wzwb_ws, s12_ws, bias_ws);
  // 3) flash attention
  attn_kernel<<<dim3(H * (S / 64)), 256, 0, stream>>>(q_ws, k_ws, v_ws, bias_ws, o_ws);
  // 4) gate split + output projection (split-bf16 MFMA)
  og_split_kernel<<<(S * D / 4 + 255) / 256, 256, 0, stream>>>(o_ws, g_ws, a_hi, a_lo);
  outproj_mfma_kernel<<<192, 256, 0, stream>>>(a_hi, a_lo, w_hi, w_lo, out);
}

// Round 12
// 335.041 us; speedup vs baseline: 5.6867x; 1.1574x over previous
//
#include <hip/hip_runtime.h>

constexpr int H  = 16;
constexpr int HD = 48;
constexpr int D  = 768;    // H*HD
constexpr int DZ = 128;
constexpr int S  = 1024;
constexpr float EPS = 1e-5f;

typedef __attribute__((ext_vector_type(8))) short bf16x8;
typedef __attribute__((ext_vector_type(4))) float f32x4;

__device__ __forceinline__ float sigmoidf_(float x) { return 1.f / (1.f + __expf(-x)); }

// f32 -> bf16 bits, round-to-nearest-even
__device__ __forceinline__ unsigned short f2b(float f) {
  unsigned u = __float_as_uint(f);
  u += 0x7FFFu + ((u >> 16) & 1u);
  return (unsigned short)(u >> 16);
}
// split x = hi + lo (both bf16); x - bf16(x) exact, residual ~2^-17 rel
__device__ __forceinline__ void split2(float x, unsigned short& h, unsigned short& l) {
  const unsigned short hb = f2b(x);
  const float hf = __uint_as_float((unsigned)hb << 16);
  h = hb;
  l = f2b(x - hf);
}
__device__ __forceinline__ unsigned pack2(unsigned short a, unsigned short b) {
  return (unsigned)a | ((unsigned)b << 16);
}

// ---------------------------------------------------------------------------
// split6: s (S*D) and 5 weights (Wq,Wk,Wv,Wg,Wo) -> bf16 hi/lo planes.
// ---------------------------------------------------------------------------
__global__ __launch_bounds__(256)
void split6_kernel(const float* __restrict__ s, const float* __restrict__ Wq,
                   const float* __restrict__ Wk, const float* __restrict__ Wv,
                   const float* __restrict__ Wg, const float* __restrict__ Wo,
                   unsigned short* __restrict__ s_hi, unsigned short* __restrict__ s_lo,
                   unsigned short* __restrict__ w_hi, unsigned short* __restrict__ w_lo) {
  const int seg = blockIdx.y;
  const float* src;
  unsigned short *dh, *dl;
  int n;
  if (seg == 0) { src = s; dh = s_hi; dl = s_lo; n = S * D; }
  else {
    src = (seg == 1) ? Wq : (seg == 2) ? Wk : (seg == 3) ? Wv : (seg == 4) ? Wg : Wo;
    dh = w_hi + (size_t)(seg - 1) * D * D;
    dl = w_lo + (size_t)(seg - 1) * D * D;
    n = D * D;
  }
  const int i4 = blockIdx.x * 256 + threadIdx.x;
  if (i4 * 4 < n) {
    const float4 v = *reinterpret_cast<const float4*>(src + (size_t)i4 * 4);
    ushort4 hh, ll;
    split2(v.x, hh.x, ll.x); split2(v.y, hh.y, ll.y);
    split2(v.z, hh.z, ll.z); split2(v.w, hh.w, ll.w);
    *reinterpret_cast<ushort4*>(dh + (size_t)i4 * 4) = hh;
    *reinterpret_cast<ushort4*>(dl + (size_t)i4 * 4) = ll;
  }
}

// zero the head-pad columns (h*64+48 .. h*64+63) of q/k hi-lo planes
__global__ __launch_bounds__(256)
void padzero_kernel(unsigned short* __restrict__ q_hi, unsigned short* __restrict__ q_lo,
                    unsigned short* __restrict__ k_hi, unsigned short* __restrict__ k_lo) {
  const int i = blockIdx.x * 256 + threadIdx.x;   // 1024 rows * 16 h * 4 ushort4
  if (i >= 1024 * 16 * 4) return;
  const int row = i >> 6, rem = i & 63;
  const int h = rem >> 2, off = (rem & 3) << 2;
  const size_t a = (size_t)row * 1024 + h * 64 + 48 + off;
  const ushort4 zz = {0, 0, 0, 0};
  *reinterpret_cast<ushort4*>(q_hi + a) = zz;
  *reinterpret_cast<ushort4*>(q_lo + a) = zz;
  *reinterpret_cast<ushort4*>(k_hi + a) = zz;
  *reinterpret_cast<ushort4*>(k_lo + a) = zz;
}

// ---------------------------------------------------------------------------
// Split-bf16 MFMA GEMM core: one wave, 32x32 tile of C = A @ W^T.
// Fragment pattern (validated): lane&15 = m/n index, (lane>>4)*8+j = k;
// D: col = lane&15, row = (lane>>4)*4 + r.
// ---------------------------------------------------------------------------
__device__ __forceinline__ void mfma_core32(const unsigned short* __restrict__ Ah,
                                            const unsigned short* __restrict__ Al,
                                            const unsigned short* __restrict__ Wh,
                                            const unsigned short* __restrict__ Wl,
                                            const int m0, const int n0,
                                            f32x4& a00, f32x4& a01, f32x4& a10, f32x4& a11) {
  const int lane = threadIdx.x & 63;
  const int r16 = lane & 15, kg = lane >> 4;
  const unsigned short* pah = Ah + (size_t)(m0 + r16) * D + kg * 8;
  const unsigned short* pal = Al + (size_t)(m0 + r16) * D + kg * 8;
  const unsigned short* pbh = Wh + (size_t)(n0 + r16) * D + kg * 8;
  const unsigned short* pbl = Wl + (size_t)(n0 + r16) * D + kg * 8;
#pragma unroll 2
  for (int k = 0; k < D; k += 32) {
    const bf16x8 ah0 = *reinterpret_cast<const bf16x8*>(pah + k);
    const bf16x8 ah1 = *reinterpret_cast<const bf16x8*>(pah + 16 * D + k);
    const bf16x8 al0 = *reinterpret_cast<const bf16x8*>(pal + k);
    const bf16x8 al1 = *reinterpret_cast<const bf16x8*>(pal + 16 * D + k);
    const bf16x8 bh0 = *reinterpret_cast<const bf16x8*>(pbh + k);
    const bf16x8 bh1 = *reinterpret_cast<const bf16x8*>(pbh + 16 * D + k);
    const bf16x8 bl0 = *reinterpret_cast<const bf16x8*>(pbl + k);
    const bf16x8 bl1 = *reinterpret_cast<const bf16x8*>(pbl + 16 * D + k);
    a00 = __builtin_amdgcn_mfma_f32_16x16x32_bf16(ah0, bh0, a00, 0, 0, 0);
    a00 = __builtin_amdgcn_mfma_f32_16x16x32_bf16(ah0, bl0, a00, 0, 0, 0);
    a00 = __builtin_amdgcn_mfma_f32_16x16x32_bf16(al0, bh0, a00, 0, 0, 0);
    a01 = __builtin_amdgcn_mfma_f32_16x16x32_bf16(ah0, bh1, a01, 0, 0, 0);
    a01 = __builtin_amdgcn_mfma_f32_16x16x32_bf16(ah0, bl1, a01, 0, 0, 0);
    a01 = __builtin_amdgcn_mfma_f32_16x16x32_bf16(al0, bh1, a01, 0, 0, 0);
    a10 = __builtin_amdgcn_mfma_f32_16x16x32_bf16(ah1, bh0, a10, 0, 0, 0);
    a10 = __builtin_amdgcn_mfma_f32_16x16x32_bf16(ah1, bl0, a10, 0, 0, 0);
    a10 = __builtin_amdgcn_mfma_f32_16x16x32_bf16(al1, bh0, a10, 0, 0, 0);
    a11 = __builtin_amdgcn_mfma_f32_16x16x32_bf16(ah1, bh1, a11, 0, 0, 0);
    a11 = __builtin_amdgcn_mfma_f32_16x16x32_bf16(ah1, bl1, a11, 0, 0, 0);
    a11 = __builtin_amdgcn_mfma_f32_16x16x32_bf16(al1, bh1, a11, 0, 0, 0);
  }
}

// qkvg: 4 weights x 768 tiles = 3072 waves. Epilogue emits attn-ready forms:
//  wsel 0 (q): (acc+bq)*scale -> hi/lo, padded row-major [s][h*64+d]
//  wsel 1 (k): hi/lo padded row-major
//  wsel 2 (v): hi/lo TRANSPOSED [col][t]  (col = h*48+d)
//  wsel 3 (g): f32 row-major
__global__ __launch_bounds__(256)
void qkvg_mfma_kernel(const unsigned short* __restrict__ s_hi,
                      const unsigned short* __restrict__ s_lo,
                      const unsigned short* __restrict__ w_hi,
                      const unsigned short* __restrict__ w_lo,
                      const float* __restrict__ bq,
                      unsigned short* __restrict__ q_hi, unsigned short* __restrict__ q_lo,
                      unsigned short* __restrict__ k_hi, unsigned short* __restrict__ k_lo,
                      unsigned short* __restrict__ vt_hi, unsigned short* __restrict__ vt_lo,
                      float* __restrict__ g_ws) {
  const int wid = blockIdx.x * 4 + (threadIdx.x >> 6);
  const int wsel = wid / 768;
  const int rr = wid % 768;
  const int m0 = (rr / 24) * 32, n0 = (rr % 24) * 32;
  f32x4 a00 = {0.f, 0.f, 0.f, 0.f}, a01 = a00, a10 = a00, a11 = a00;
  mfma_core32(s_hi, s_lo, w_hi + (size_t)wsel * D * D, w_lo + (size_t)wsel * D * D,
              m0, n0, a00, a01, a10, a11);
  const int lane = threadIdx.x & 63;
  const int r16 = lane & 15, kg = lane >> 4;
  const float scale = 0.14433756729740643f;  // 1/sqrt(48)
#pragma unroll
  for (int half = 0; half < 2; ++half) {
#pragma unroll
    for (int rh = 0; rh < 2; ++rh) {
      const f32x4 acc = (half == 0) ? (rh == 0 ? a00 : a10) : (rh == 0 ? a01 : a11);
      const int col = n0 + half * 16 + r16;
#pragma unroll
      for (int r = 0; r < 4; ++r) {
        const int row = m0 + rh * 16 + kg * 4 + r;
        float val = acc[r];
        if (wsel == 0) val = (val + bq[col]) * scale;
        if (wsel <= 1) {
          const int hcol = (col / 48) * 64 + (col % 48);
          unsigned short hh, ll;
          split2(val, hh, ll);
          unsigned short* dh = (wsel == 0) ? q_hi : k_hi;
          unsigned short* dl = (wsel == 0) ? q_lo : k_lo;
          dh[(size_t)row * 1024 + hcol] = hh;
          dl[(size_t)row * 1024 + hcol] = ll;
        } else if (wsel == 2) {
          unsigned short hh, ll;
          split2(val, hh, ll);
          vt_hi[(size_t)col * 1024 + row] = hh;
          vt_lo[(size_t)col * 1024 + row] = ll;
        } else {
          g_ws[(size_t)row * D + col] = val;
        }
      }
    }
  }
}

// outproj: 768 waves = 192 blocks; A = gated activations (a_hi/a_lo), W = Wo.
__global__ __launch_bounds__(256)
void outproj_mfma_kernel(const unsigned short* __restrict__ a_hi,
                         const unsigned short* __restrict__ a_lo,
                         const unsigned short* __restrict__ w_hi,
                         const unsigned short* __restrict__ w_lo,
                         float* __restrict__ out) {
  const int wid = blockIdx.x * 4 + (threadIdx.x >> 6);
  const int m0 = (wid / 24) * 32, n0 = (wid % 24) * 32;
  f32x4 a00 = {0.f, 0.f, 0.f, 0.f}, a01 = a00, a10 = a00, a11 = a00;
  mfma_core32(a_hi, a_lo, w_hi + (size_t)4 * D * D, w_lo + (size_t)4 * D * D,
              m0, n0, a00, a01, a10, a11);
  const int lane = threadIdx.x & 63;
  const int r16 = lane & 15, kg = lane >> 4;
#pragma unroll
  for (int r = 0; r < 4; ++r) {
    const int row0 = m0 + kg * 4 + r;
    out[(size_t)row0 * D + n0 + r16] = a00[r];
    out[(size_t)row0 * D + n0 + 16 + r16] = a01[r];
    out[(size_t)(row0 + 16) * D + n0 + r16] = a10[r];
    out[(size_t)(row0 + 16) * D + n0 + 16 + r16] = a11[r];
  }
}

// ---------------------------------------------------------------------------
// pair-bias prep (unchanged from round 10)
// ---------------------------------------------------------------------------
__global__ __launch_bounds__(256)
void pb_prep_kernel(const float* __restrict__ Wz, const float* __restrict__ ln_w,
                    const float* __restrict__ ln_b, unsigned short* __restrict__ wzwb,
                    float* __restrict__ s12) {
  const int t = threadIdx.x;
  for (int e = t; e < 16 * DZ; e += 256) wzwb[e] = f2b(Wz[e] * ln_w[e & 127]);
  __syncthreads();
  if (t < 32) {
    const int h = t & 15;
    float a = 0.f;
    if (t < 16) {
      for (int c = 0; c < DZ; ++c) {
        const unsigned u = (unsigned)wzwb[h * DZ + c] << 16;
        a += __uint_as_float(u);
      }
    } else {
      for (int c = 0; c < DZ; ++c) a += Wz[h * DZ + c] * ln_b[c];
    }
    s12[t] = a;
  }
}

// ---------------------------------------------------------------------------
// Pair bias v9 (MFMA, LN folded into epilogue) — unchanged from round 10.
// ---------------------------------------------------------------------------
__global__ __launch_bounds__(256)
void pair_bias_kernel(const float* __restrict__ z, const unsigned short* __restrict__ wzwb,
                      const float* __restrict__ s12, float* __restrict__ bias_out) {
  __shared__ float T[4][64 * 17];
  const int tid = threadIdx.x;
  const int lane = tid & 63;
  const int wv = tid >> 6;
  const int hq = lane & 15;
  const int grp = lane >> 4;

  bf16x8 bf[4];
#pragma unroll
  for (int m = 0; m < 4; ++m)
    bf[m] = *reinterpret_cast<const bf16x8*>(wzwb + hq * DZ + m * 32 + grp * 8);
  const float S1h = s12[hq], S2h = s12[16 + hq];

  const int chunk = blockIdx.x * 4 + wv;
  const size_t p0 = (size_t)chunk * 64;
  float* Tw = &T[wv][0];

#pragma unroll 1
  for (int sub = 0; sub < 4; ++sub) {
    const float* zr = z + (p0 + sub * 16 + hq) * DZ + grp * 8;
    f32x4 acc = {0.f, 0.f, 0.f, 0.f};
    float s1 = 0.f, s2 = 0.f;
#pragma unroll
    for (int m = 0; m < 4; ++m) {
      const float4 a0 = *reinterpret_cast<const float4*>(zr + m * 32);
      const float4 a1 = *reinterpret_cast<const float4*>(zr + m * 32 + 4);
      s1 += (a0.x + a0.y) + (a0.z + a0.w) + (a1.x + a1.y) + (a1.z + a1.w);
      s2 = fmaf(a0.x, a0.x, fmaf(a0.y, a0.y, fmaf(a0.z, a0.z, fmaf(a0.w, a0.w, s2))));
      s2 = fmaf(a1.x, a1.x, fmaf(a1.y, a1.y, fmaf(a1.z, a1.z, fmaf(a1.w, a1.w, s2))));
      bf16x8 af;
      af[0] = (short)f2b(a0.x); af[1] = (short)f2b(a0.y);
      af[2] = (short)f2b(a0.z); af[3] = (short)f2b(a0.w);
      af[4] = (short)f2b(a1.x); af[5] = (short)f2b(a1.y);
      af[6] = (short)f2b(a1.z); af[7] = (short)f2b(a1.w);
      acc = __builtin_amdgcn_mfma_f32_16x16x32_bf16(af, bf[m], acc, 0, 0, 0);
    }
    s1 += __shfl_xor(s1, 16); s1 += __shfl_xor(s1, 32);
    s2 += __shfl_xor(s2, 16); s2 += __shfl_xor(s2, 32);
    const float mu = s1 * (1.f / DZ);
    const float inv = rsqrtf(s2 * (1.f / DZ) - mu * mu + EPS);
#pragma unroll
    for (int r = 0; r < 4; ++r) {
      const int st = grp * 4 + r;
      const float mur = __shfl(mu, st);
      const float invr = __shfl(inv, st);
      Tw[(sub * 16 + st) * 17 + hq] = invr * (acc[r] - mur * S1h) + S2h;
    }
  }
#pragma unroll
  for (int hh = 0; hh < 16; ++hh)
    bias_out[(size_t)hh * S * S + p0 + lane] = Tw[lane * 17 + hh];
}

// ---------------------------------------------------------------------------
// Attention v2: split-bf16 MFMA flash attention, gate fused into epilogue.
// Block = (h, 64 q rows), 4 waves; wave owns 16 q rows. Per 64-t tile:
//   QK^T transposed: D[t][s] = mfma(K-frag, Q-frag, bias4) — bias enters as
//   the MFMA C operand (f32x4 load matches D row layout t=kg*4+r, col s).
//   Softmax: in-lane 16-max + shfl_xor(16,32); P split hi/lo, packed pairs
//   into wave-private LDS [16][72] u16 (no barriers). PV: D2[s][d] =
//   mfma(P-frag from LDS, V-frag from global vt planes). 3-term split
//   products throughout (hi*hi + hi*lo + lo*hi) for f32-grade accuracy.
// Epilogue: o = accO/l, a = o*sigmoid(g) -> split -> a_hi/a_lo.
// ---------------------------------------------------------------------------
constexpr int PST = 72;   // P slab stride (u16)

__global__ __launch_bounds__(256)
void attn_kernel(const unsigned short* __restrict__ q_hi, const unsigned short* __restrict__ q_lo,
                 const unsigned short* __restrict__ k_hi, const unsigned short* __restrict__ k_lo,
                 const unsigned short* __restrict__ vt_hi, const unsigned short* __restrict__ vt_lo,
                 const float* __restrict__ bias, const float* __restrict__ g,
                 unsigned short* __restrict__ a_hi, unsigned short* __restrict__ a_lo) {
  __shared__ unsigned short Ph[4][16 * PST], Pl[4][16 * PST];
  const int lane = threadIdx.x & 63;
  const int wv = threadIdx.x >> 6;
  const int h = blockIdx.x >> 4;
  const int q0 = ((blockIdx.x & 15) << 6) + wv * 16;
  const int n16 = lane & 15, kg = lane >> 4;

  // Q B-fragments (padded row-major [s][h*64+d]), loaded once
  const size_t qb = (size_t)(q0 + n16) * 1024 + h * 64;
  const bf16x8 qh0 = *reinterpret_cast<const bf16x8*>(q_hi + qb + kg * 8);
  const bf16x8 qh1 = *reinterpret_cast<const bf16x8*>(q_hi + qb + 32 + kg * 8);
  const bf16x8 ql0 = *reinterpret_cast<const bf16x8*>(q_lo + qb + kg * 8);
  const bf16x8 ql1 = *reinterpret_cast<const bf16x8*>(q_lo + qb + 32 + kg * 8);

  float mrow = -1e30f, lrow = 0.f;
  f32x4 accO[3] = {};
  unsigned short* php = Ph[wv];
  unsigned short* plp = Pl[wv];

#pragma unroll 1
  for (int t0 = 0; t0 < S; t0 += 64) {
    // QK^T: 4 sub-tiles of 16 t
    f32x4 sc[4];
#pragma unroll
    for (int ts = 0; ts < 4; ++ts) {
      const size_t kb = (size_t)(t0 + ts * 16 + n16) * 1024 + h * 64;
      const bf16x8 kh0 = *reinterpret_cast<const bf16x8*>(k_hi + kb + kg * 8);
      const bf16x8 kh1 = *reinterpret_cast<const bf16x8*>(k_hi + kb + 32 + kg * 8);
      const bf16x8 kl0 = *reinterpret_cast<const bf16x8*>(k_lo + kb + kg * 8);
      const bf16x8 kl1 = *reinterpret_cast<const bf16x8*>(k_lo + kb + 32 + kg * 8);
      f32x4 a = *reinterpret_cast<const f32x4*>(
          bias + ((size_t)h * S + (q0 + n16)) * S + t0 + ts * 16 + kg * 4);
      a = __builtin_amdgcn_mfma_f32_16x16x32_bf16(kh0, qh0, a, 0, 0, 0);
      a = __builtin_amdgcn_mfma_f32_16x16x32_bf16(kh1, qh1, a, 0, 0, 0);
      a = __builtin_amdgcn_mfma_f32_16x16x32_bf16(kh0, ql0, a, 0, 0, 0);
      a = __builtin_amdgcn_mfma_f32_16x16x32_bf16(kh1, ql1, a, 0, 0, 0);
      a = __builtin_amdgcn_mfma_f32_16x16x32_bf16(kl0, qh0, a, 0, 0, 0);
      a = __builtin_amdgcn_mfma_f32_16x16x32_bf16(kl1, qh1, a, 0, 0, 0);
      sc[ts] = a;
    }

    // online softmax over this tile's 64 t
    float tmax = sc[0][0];
#pragma unroll
    for (int ts = 0; ts < 4; ++ts)
#pragma unroll
      for (int r = 0; r < 4; ++r) tmax = fmaxf(tmax, sc[ts][r]);
    tmax = fmaxf(tmax, __shfl_xor(tmax, 16));
    tmax = fmaxf(tmax, __shfl_xor(tmax, 32));
    const float mn = fmaxf(mrow, tmax);
    const float fac = __expf(mrow - mn);
    mrow = mn;
    float psum = 0.f;
#pragma unroll
    for (int ts = 0; ts < 4; ++ts) {
      const float p0 = __expf(sc[ts][0] - mn), p1 = __expf(sc[ts][1] - mn);
      const float p2 = __expf(sc[ts][2] - mn), p3 = __expf(sc[ts][3] - mn);
      psum += (p0 + p1) + (p2 + p3);
      unsigned short h0, l0, h1, l1, h2, l2, h3, l3;
      split2(p0, h0, l0); split2(p1, h1, l1); split2(p2, h2, l2); split2(p3, h3, l3);
      const int ti = ts * 16 + kg * 4;
      unsigned* wh = reinterpret_cast<unsigned*>(&php[n16 * PST + ti]);
      unsigned* wl = reinterpret_cast<unsigned*>(&plp[n16 * PST + ti]);
      wh[0] = pack2(h0, h1); wh[1] = pack2(h2, h3);
      wl[0] = pack2(l0, l1); wl[1] = pack2(l2, l3);
    }
    lrow = lrow * fac + psum;

    // rescale accO (rows s' = kg*4+r)
    float facr[4];
#pragma unroll
    for (int r = 0; r < 4; ++r) facr[r] = __shfl(fac, kg * 4 + r);
#pragma unroll
    for (int ds = 0; ds < 3; ++ds)
#pragma unroll
      for (int r = 0; r < 4; ++r) accO[ds][r] *= facr[r];

    // PV over the tile (2 K=32 chunks)
#pragma unroll
    for (int c = 0; c < 2; ++c) {
      const bf16x8 pah = *reinterpret_cast<const bf16x8*>(&php[n16 * PST + c * 32 + kg * 8]);
      const bf16x8 pal = *reinterpret_cast<const bf16x8*>(&plp[n16 * PST + c * 32 + kg * 8]);
#pragma unroll
      for (int ds = 0; ds < 3; ++ds) {
        const size_t vb = (size_t)(h * 48 + ds * 16 + n16) * 1024 + t0 + c * 32 + kg * 8;
        const bf16x8 vh = *reinterpret_cast<const bf16x8*>(vt_hi + vb);
        const bf16x8 vl = *reinterpret_cast<const bf16x8*>(vt_lo + vb);
        accO[ds] = __builtin_amdgcn_mfma_f32_16x16x32_bf16(pah, vh, accO[ds], 0, 0, 0);
        accO[ds] = __builtin_amdgcn_mfma_f32_16x16x32_bf16(pah, vl, accO[ds], 0, 0, 0);
        accO[ds] = __builtin_amdgcn_mfma_f32_16x16x32_bf16(pal, vh, accO[ds], 0, 0, 0);
      }
    }
  }

  // finalize: row sums, normalize, gate, split-store
  lrow += __shfl_xor(lrow, 16);
  lrow += __shfl_xor(lrow, 32);
  const float rl = 1.f / lrow;
  float rlr[4];
#pragma unroll
  for (int r = 0; r < 4; ++r) rlr[r] = __shfl(rl, kg * 4 + r);
#pragma unroll
  for (int ds = 0; ds < 3; ++ds)
#pragma unroll
    for (int r = 0; r < 4; ++r) {
      const size_t idx = (size_t)(q0 + kg * 4 + r) * D + h * 48 + ds * 16 + n16;
      const float o = accO[ds][r] * rlr[r];
      const float a = o * sigmoidf_(g[idx]);
      unsigned short hh, ll;
      split2(a, hh, ll);
      a_hi[idx] = hh;
      a_lo[idx] = ll;
    }
}

extern "C" void kernel_launch(void* const* d_in, const int* in_sizes, int n_in,
                              void* d_out, int out_size, void* d_ws, size_t ws_size,
                              hipStream_t stream) {
  const float* s    = (const float*)d_in[0];
  const float* z    = (const float*)d_in[1];
  const float* Wq   = (const float*)d_in[2];
  const float* bq   = (const float*)d_in[3];
  const float* Wk   = (const float*)d_in[4];
  const float* Wv   = (const float*)d_in[5];
  const float* Wg   = (const float*)d_in[6];
  const float* ln_w = (const float*)d_in[7];
  const float* ln_b = (const float*)d_in[8];
  const float* Wz   = (const float*)d_in[9];
  const float* Wo   = (const float*)d_in[10];
  float* out = (float*)d_out;

  // workspace layout
  float* g_ws    = (float*)d_ws;                                  // S*D f32
  float* bias_ws = g_ws + (size_t)S * D;                          // H*S*S f32
  unsigned short* wzwb_ws = (unsigned short*)(bias_ws + (size_t)H * S * S);  // 2048 u16
  float* s12_ws  = bias_ws + (size_t)H * S * S + 1024;            // 32 f32
  unsigned short* s_hi = (unsigned short*)(s12_ws + 32);
  unsigned short* s_lo = s_hi + (size_t)S * D;
  unsigned short* w_hi = s_lo + (size_t)S * D;
  unsigned short* w_lo = w_hi + (size_t)5 * D * D;
  unsigned short* a_hi = w_lo + (size_t)5 * D * D;
  unsigned short* a_lo = a_hi + (size_t)S * D;
  unsigned short* q_hi = a_lo + (size_t)S * D;                    // [S][1024] padded
  unsigned short* q_lo = q_hi + (size_t)S * 1024;
  unsigned short* k_hi = q_lo + (size_t)S * 1024;
  unsigned short* k_lo = k_hi + (size_t)S * 1024;
  unsigned short* vt_hi = k_lo + (size_t)S * 1024;                // [768][1024]
  unsigned short* vt_lo = vt_hi + (size_t)D * 1024;

  // 0) splits + pad-zero
  split6_kernel<<<dim3((S * D / 4 + 255) / 256, 6), 256, 0, stream>>>(
      s, Wq, Wk, Wv, Wg, Wo, s_hi, s_lo, w_hi, w_lo);
  padzero_kernel<<<(1024 * 16 * 4) / 256, 256, 0, stream>>>(q_hi, q_lo, k_hi, k_lo);
  // 1) QKVG projections (split-bf16 MFMA, attn-ready epilogue)
  qkvg_mfma_kernel<<<768, 256, 0, stream>>>(s_hi, s_lo, w_hi, w_lo, bq,
                                            q_hi, q_lo, k_hi, k_lo, vt_hi, vt_lo, g_ws);
  // 2) pair bias
  pb_prep_kernel<<<1, 256, 0, stream>>>(Wz, ln_w, ln_b, wzwb_ws, s12_ws);
  pair_bias_kernel<<<4096, 256, 0, stream>>>(z, wzwb_ws, s12_ws, bias_ws);
  // 3) MFMA flash attention (gate fused)
  attn_kernel<<<dim3(H * (S / 64)), 256, 0, stream>>>(q_hi, q_lo, k_hi, k_lo,
                                                      vt_hi, vt_lo, bias_ws, g_ws,
                                                      a_hi, a_lo);
  // 4) output projection
  outproj_mfma_kernel<<<192, 256, 0, stream>>>(a_hi, a_lo, w_hi, w_lo, out);
}

// Round 13
// 333.670 us; speedup vs baseline: 5.7101x; 1.0041x over previous
//
#include <hip/hip_runtime.h>

constexpr int H  = 16;
constexpr int HD = 48;
constexpr int D  = 768;    // H*HD
constexpr int DZ = 128;
constexpr int S  = 1024;
constexpr float EPS = 1e-5f;

typedef __attribute__((ext_vector_type(8))) short bf16x8;
typedef __attribute__((ext_vector_type(4))) float f32x4;

__device__ __forceinline__ float sigmoidf_(float x) { return 1.f / (1.f + __expf(-x)); }

__device__ __forceinline__ unsigned short f2b(float f) {
  unsigned u = __float_as_uint(f);
  u += 0x7FFFu + ((u >> 16) & 1u);
  return (unsigned short)(u >> 16);
}
__device__ __forceinline__ void split2(float x, unsigned short& h, unsigned short& l) {
  const unsigned short hb = f2b(x);
  const float hf = __uint_as_float((unsigned)hb << 16);
  h = hb;
  l = f2b(x - hf);
}
__device__ __forceinline__ unsigned pack2(unsigned short a, unsigned short b) {
  return (unsigned)a | ((unsigned)b << 16);
}

// ===========================================================================
// Kernel A: split6 (s + 5 weights -> bf16 hi/lo planes) + pb_prep.
// grid dim3(769, 6); block (768, y==0) runs pb_prep.
// ===========================================================================
__global__ __launch_bounds__(256)
void prep_kernel(const float* __restrict__ s, const float* __restrict__ Wq,
                 const float* __restrict__ Wk, const float* __restrict__ Wv,
                 const float* __restrict__ Wg, const float* __restrict__ Wo,
                 unsigned short* __restrict__ s_hi, unsigned short* __restrict__ s_lo,
                 unsigned short* __restrict__ w_hi, unsigned short* __restrict__ w_lo,
                 const float* __restrict__ Wz, const float* __restrict__ ln_w,
                 const float* __restrict__ ln_b, unsigned short* __restrict__ wzwb,
                 float* __restrict__ s12) {
  if (blockIdx.x == 768) {
    if (blockIdx.y != 0) return;
    // pb_prep: wzwb = bf16(Wz*ln_w); S1 = sum(rounded); S2 = sum(ln_b*Wz)
    const int t = threadIdx.x;
    for (int e = t; e < 16 * DZ; e += 256) wzwb[e] = f2b(Wz[e] * ln_w[e & 127]);
    __syncthreads();
    if (t < 32) {
      const int h = t & 15;
      float a = 0.f;
      if (t < 16) {
        for (int c = 0; c < DZ; ++c) {
          const unsigned u = (unsigned)wzwb[h * DZ + c] << 16;
          a += __uint_as_float(u);
        }
      } else {
        for (int c = 0; c < DZ; ++c) a += Wz[h * DZ + c] * ln_b[c];
      }
      s12[t] = a;
    }
    return;
  }
  const int seg = blockIdx.y;
  const float* src;
  unsigned short *dh, *dl;
  int n;
  if (seg == 0) { src = s; dh = s_hi; dl = s_lo; n = S * D; }
  else {
    src = (seg == 1) ? Wq : (seg == 2) ? Wk : (seg == 3) ? Wv : (seg == 4) ? Wg : Wo;
    dh = w_hi + (size_t)(seg - 1) * D * D;
    dl = w_lo + (size_t)(seg - 1) * D * D;
    n = D * D;
  }
  const int i4 = blockIdx.x * 256 + threadIdx.x;
  if (i4 * 4 < n) {
    const float4 v = *reinterpret_cast<const float4*>(src + (size_t)i4 * 4);
    ushort4 hh, ll;
    split2(v.x, hh.x, ll.x); split2(v.y, hh.y, ll.y);
    split2(v.z, hh.z, ll.z); split2(v.w, hh.w, ll.w);
    *reinterpret_cast<ushort4*>(dh + (size_t)i4 * 4) = hh;
    *reinterpret_cast<ushort4*>(dl + (size_t)i4 * 4) = ll;
  }
}

// ---------------------------------------------------------------------------
// Split-bf16 MFMA GEMM core (32x32 tile/wave). Fragment pattern (validated):
// lane&15 = m/n index, (lane>>4)*8+j = k; D: col = lane&15, row=(lane>>4)*4+r.
// ---------------------------------------------------------------------------
__device__ __forceinline__ void mfma_core32(const unsigned short* __restrict__ Ah,
                                            const unsigned short* __restrict__ Al,
                                            const unsigned short* __restrict__ Wh,
                                            const unsigned short* __restrict__ Wl,
                                            const int m0, const int n0,
                                            f32x4& a00, f32x4& a01, f32x4& a10, f32x4& a11) {
  const int lane = threadIdx.x & 63;
  const int r16 = lane & 15, kg = lane >> 4;
  const unsigned short* pah = Ah + (size_t)(m0 + r16) * D + kg * 8;
  const unsigned short* pal = Al + (size_t)(m0 + r16) * D + kg * 8;
  const unsigned short* pbh = Wh + (size_t)(n0 + r16) * D + kg * 8;
  const unsigned short* pbl = Wl + (size_t)(n0 + r16) * D + kg * 8;
#pragma unroll 2
  for (int k = 0; k < D; k += 32) {
    const bf16x8 ah0 = *reinterpret_cast<const bf16x8*>(pah + k);
    const bf16x8 ah1 = *reinterpret_cast<const bf16x8*>(pah + 16 * D + k);
    const bf16x8 al0 = *reinterpret_cast<const bf16x8*>(pal + k);
    const bf16x8 al1 = *reinterpret_cast<const bf16x8*>(pal + 16 * D + k);
    const bf16x8 bh0 = *reinterpret_cast<const bf16x8*>(pbh + k);
    const bf16x8 bh1 = *reinterpret_cast<const bf16x8*>(pbh + 16 * D + k);
    const bf16x8 bl0 = *reinterpret_cast<const bf16x8*>(pbl + k);
    const bf16x8 bl1 = *reinterpret_cast<const bf16x8*>(pbl + 16 * D + k);
    a00 = __builtin_amdgcn_mfma_f32_16x16x32_bf16(ah0, bh0, a00, 0, 0, 0);
    a00 = __builtin_amdgcn_mfma_f32_16x16x32_bf16(ah0, bl0, a00, 0, 0, 0);
    a00 = __builtin_amdgcn_mfma_f32_16x16x32_bf16(al0, bh0, a00, 0, 0, 0);
    a01 = __builtin_amdgcn_mfma_f32_16x16x32_bf16(ah0, bh1, a01, 0, 0, 0);
    a01 = __builtin_amdgcn_mfma_f32_16x16x32_bf16(ah0, bl1, a01, 0, 0, 0);
    a01 = __builtin_amdgcn_mfma_f32_16x16x32_bf16(al0, bh1, a01, 0, 0, 0);
    a10 = __builtin_amdgcn_mfma_f32_16x16x32_bf16(ah1, bh0, a10, 0, 0, 0);
    a10 = __builtin_amdgcn_mfma_f32_16x16x32_bf16(ah1, bl0, a10, 0, 0, 0);
    a10 = __builtin_amdgcn_mfma_f32_16x16x32_bf16(al1, bh0, a10, 0, 0, 0);
    a11 = __builtin_amdgcn_mfma_f32_16x16x32_bf16(ah1, bh1, a11, 0, 0, 0);
    a11 = __builtin_amdgcn_mfma_f32_16x16x32_bf16(ah1, bl1, a11, 0, 0, 0);
    a11 = __builtin_amdgcn_mfma_f32_16x16x32_bf16(al1, bh1, a11, 0, 0, 0);
  }
}

// ---------------------------------------------------------------------------
// qkvg body (wid 0..3071): attn-ready epilogues (q/k padded hi/lo, v
// transposed hi/lo, g f32).
// ---------------------------------------------------------------------------
__device__ __forceinline__ void qkvg_body(const int wid,
    const unsigned short* __restrict__ s_hi, const unsigned short* __restrict__ s_lo,
    const unsigned short* __restrict__ w_hi, const unsigned short* __restrict__ w_lo,
    const float* __restrict__ bq,
    unsigned short* __restrict__ q_hi, unsigned short* __restrict__ q_lo,
    unsigned short* __restrict__ k_hi, unsigned short* __restrict__ k_lo,
    unsigned short* __restrict__ vt_hi, unsigned short* __restrict__ vt_lo,
    float* __restrict__ g_ws) {
  const int wsel = wid / 768;
  const int rr = wid % 768;
  const int m0 = (rr / 24) * 32, n0 = (rr % 24) * 32;
  f32x4 a00 = {0.f, 0.f, 0.f, 0.f}, a01 = a00, a10 = a00, a11 = a00;
  mfma_core32(s_hi, s_lo, w_hi + (size_t)wsel * D * D, w_lo + (size_t)wsel * D * D,
              m0, n0, a00, a01, a10, a11);
  const int lane = threadIdx.x & 63;
  const int r16 = lane & 15, kg = lane >> 4;
  const float scale = 0.14433756729740643f;  // 1/sqrt(48)
#pragma unroll
  for (int half = 0; half < 2; ++half) {
#pragma unroll
    for (int rh = 0; rh < 2; ++rh) {
      const f32x4 acc = (half == 0) ? (rh == 0 ? a00 : a10) : (rh == 0 ? a01 : a11);
      const int col = n0 + half * 16 + r16;
#pragma unroll
      for (int r = 0; r < 4; ++r) {
        const int row = m0 + rh * 16 + kg * 4 + r;
        float val = acc[r];
        if (wsel == 0) val = (val + bq[col]) * scale;
        if (wsel <= 1) {
          const int hcol = (col / 48) * 64 + (col % 48);
          unsigned short hh, ll;
          split2(val, hh, ll);
          unsigned short* dh = (wsel == 0) ? q_hi : k_hi;
          unsigned short* dl = (wsel == 0) ? q_lo : k_lo;
          dh[(size_t)row * 1024 + hcol] = hh;
          dl[(size_t)row * 1024 + hcol] = ll;
        } else if (wsel == 2) {
          unsigned short hh, ll;
          split2(val, hh, ll);
          vt_hi[(size_t)col * 1024 + row] = hh;
          vt_lo[(size_t)col * 1024 + row] = ll;
        } else {
          g_ws[(size_t)row * D + col] = val;
        }
      }
    }
  }
}

// ---------------------------------------------------------------------------
// pair_bias body (chunk 0..16383): MFMA z@WzW^T with LN folded into epilogue.
// ---------------------------------------------------------------------------
__device__ __forceinline__ void pair_bias_body(const int blk,
    const float* __restrict__ z, const unsigned short* __restrict__ wzwb,
    const float* __restrict__ s12, float* __restrict__ bias_out) {
  __shared__ float T[4][64 * 17];
  const int tid = threadIdx.x;
  const int lane = tid & 63;
  const int wv = tid >> 6;
  const int hq = lane & 15;
  const int grp = lane >> 4;

  bf16x8 bf[4];
#pragma unroll
  for (int m = 0; m < 4; ++m)
    bf[m] = *reinterpret_cast<const bf16x8*>(wzwb + hq * DZ + m * 32 + grp * 8);
  const float S1h = s12[hq], S2h = s12[16 + hq];

  const int chunk = blk * 4 + wv;
  const size_t p0 = (size_t)chunk * 64;
  float* Tw = &T[wv][0];

#pragma unroll 1
  for (int sub = 0; sub < 4; ++sub) {
    const float* zr = z + (p0 + sub * 16 + hq) * DZ + grp * 8;
    f32x4 acc = {0.f, 0.f, 0.f, 0.f};
    float s1 = 0.f, s2 = 0.f;
#pragma unroll
    for (int m = 0; m < 4; ++m) {
      const float4 a0 = *reinterpret_cast<const float4*>(zr + m * 32);
      const float4 a1 = *reinterpret_cast<const float4*>(zr + m * 32 + 4);
      s1 += (a0.x + a0.y) + (a0.z + a0.w) + (a1.x + a1.y) + (a1.z + a1.w);
      s2 = fmaf(a0.x, a0.x, fmaf(a0.y, a0.y, fmaf(a0.z, a0.z, fmaf(a0.w, a0.w, s2))));
      s2 = fmaf(a1.x, a1.x, fmaf(a1.y, a1.y, fmaf(a1.z, a1.z, fmaf(a1.w, a1.w, s2))));
      bf16x8 af;
      af[0] = (short)f2b(a0.x); af[1] = (short)f2b(a0.y);
      af[2] = (short)f2b(a0.z); af[3] = (short)f2b(a0.w);
      af[4] = (short)f2b(a1.x); af[5] = (short)f2b(a1.y);
      af[6] = (short)f2b(a1.z); af[7] = (short)f2b(a1.w);
      acc = __builtin_amdgcn_mfma_f32_16x16x32_bf16(af, bf[m], acc, 0, 0, 0);
    }
    s1 += __shfl_xor(s1, 16); s1 += __shfl_xor(s1, 32);
    s2 += __shfl_xor(s2, 16); s2 += __shfl_xor(s2, 32);
    const float mu = s1 * (1.f / DZ);
    const float inv = rsqrtf(s2 * (1.f / DZ) - mu * mu + EPS);
#pragma unroll
    for (int r = 0; r < 4; ++r) {
      const int st = grp * 4 + r;
      const float mur = __shfl(mu, st);
      const float invr = __shfl(inv, st);
      Tw[(sub * 16 + st) * 17 + hq] = invr * (acc[r] - mur * S1h) + S2h;
    }
  }
#pragma unroll
  for (int hh = 0; hh < 16; ++hh)
    bias_out[(size_t)hh * S * S + p0 + lane] = Tw[lane * 17 + hh];
}

// ===========================================================================
// Kernel B: fused pair_bias (blocks 0..4095) + qkvg (4096..4863) + padzero
// (4864..5119). pair_bias first: HBM stream saturates while qkvg's MFMA/L2
// work fills the compute pipes — overlap instead of serial sum.
// ===========================================================================
__global__ __launch_bounds__(256)
void main_fused_kernel(const float* __restrict__ z, const unsigned short* __restrict__ wzwb,
                       const float* __restrict__ s12, float* __restrict__ bias_out,
                       const unsigned short* __restrict__ s_hi, const unsigned short* __restrict__ s_lo,
                       const unsigned short* __restrict__ w_hi, const unsigned short* __restrict__ w_lo,
                       const float* __restrict__ bq,
                       unsigned short* __restrict__ q_hi, unsigned short* __restrict__ q_lo,
                       unsigned short* __restrict__ k_hi, unsigned short* __restrict__ k_lo,
                       unsigned short* __restrict__ vt_hi, unsigned short* __restrict__ vt_lo,
                       float* __restrict__ g_ws) {
  const int bid = blockIdx.x;
  if (bid < 4096) {
    pair_bias_body(bid, z, wzwb, s12, bias_out);
  } else if (bid < 4864) {
    qkvg_body((bid - 4096) * 4 + (threadIdx.x >> 6), s_hi, s_lo, w_hi, w_lo, bq,
              q_hi, q_lo, k_hi, k_lo, vt_hi, vt_lo, g_ws);
  } else {
    const int i = (bid - 4864) * 256 + threadIdx.x;   // 1024 rows * 16 h * 4
    if (i < 1024 * 16 * 4) {
      const int row = i >> 6, rem = i & 63;
      const int h = rem >> 2, off = (rem & 3) << 2;
      const size_t a = (size_t)row * 1024 + h * 64 + 48 + off;
      const ushort4 zz = {0, 0, 0, 0};
      *reinterpret_cast<ushort4*>(q_hi + a) = zz;
      *reinterpret_cast<ushort4*>(q_lo + a) = zz;
      *reinterpret_cast<ushort4*>(k_hi + a) = zz;
      *reinterpret_cast<ushort4*>(k_lo + a) = zz;
    }
  }
}

// ===========================================================================
// Attention v2 (unchanged from round 12): split-bf16 MFMA flash attention,
// gate fused into epilogue.
// ===========================================================================
constexpr int PST = 72;   // P slab stride (u16)

__global__ __launch_bounds__(256)
void attn_kernel(const unsigned short* __restrict__ q_hi, const unsigned short* __restrict__ q_lo,
                 const unsigned short* __restrict__ k_hi, const unsigned short* __restrict__ k_lo,
                 const unsigned short* __restrict__ vt_hi, const unsigned short* __restrict__ vt_lo,
                 const float* __restrict__ bias, const float* __restrict__ g,
                 unsigned short* __restrict__ a_hi, unsigned short* __restrict__ a_lo) {
  __shared__ unsigned short Ph[4][16 * PST], Pl[4][16 * PST];
  const int lane = threadIdx.x & 63;
  const int wv = threadIdx.x >> 6;
  const int h = blockIdx.x >> 4;
  const int q0 = ((blockIdx.x & 15) << 6) + wv * 16;
  const int n16 = lane & 15, kg = lane >> 4;

  const size_t qb = (size_t)(q0 + n16) * 1024 + h * 64;
  const bf16x8 qh0 = *reinterpret_cast<const bf16x8*>(q_hi + qb + kg * 8);
  const bf16x8 qh1 = *reinterpret_cast<const bf16x8*>(q_hi + qb + 32 + kg * 8);
  const bf16x8 ql0 = *reinterpret_cast<const bf16x8*>(q_lo + qb + kg * 8);
  const bf16x8 ql1 = *reinterpret_cast<const bf16x8*>(q_lo + qb + 32 + kg * 8);

  float mrow = -1e30f, lrow = 0.f;
  f32x4 accO[3] = {};
  unsigned short* php = Ph[wv];
  unsigned short* plp = Pl[wv];

#pragma unroll 1
  for (int t0 = 0; t0 < S; t0 += 64) {
    f32x4 sc[4];
#pragma unroll
    for (int ts = 0; ts < 4; ++ts) {
      const size_t kb = (size_t)(t0 + ts * 16 + n16) * 1024 + h * 64;
      const bf16x8 kh0 = *reinterpret_cast<const bf16x8*>(k_hi + kb + kg * 8);
      const bf16x8 kh1 = *reinterpret_cast<const bf16x8*>(k_hi + kb + 32 + kg * 8);
      const bf16x8 kl0 = *reinterpret_cast<const bf16x8*>(k_lo + kb + kg * 8);
      const bf16x8 kl1 = *reinterpret_cast<const bf16x8*>(k_lo + kb + 32 + kg * 8);
      f32x4 a = *reinterpret_cast<const f32x4*>(
          bias + ((size_t)h * S + (q0 + n16)) * S + t0 + ts * 16 + kg * 4);
      a = __builtin_amdgcn_mfma_f32_16x16x32_bf16(kh0, qh0, a, 0, 0, 0);
      a = __builtin_amdgcn_mfma_f32_16x16x32_bf16(kh1, qh1, a, 0, 0, 0);
      a = __builtin_amdgcn_mfma_f32_16x16x32_bf16(kh0, ql0, a, 0, 0, 0);
      a = __builtin_amdgcn_mfma_f32_16x16x32_bf16(kh1, ql1, a, 0, 0, 0);
      a = __builtin_amdgcn_mfma_f32_16x16x32_bf16(kl0, qh0, a, 0, 0, 0);
      a = __builtin_amdgcn_mfma_f32_16x16x32_bf16(kl1, qh1, a, 0, 0, 0);
      sc[ts] = a;
    }

    float tmax = sc[0][0];
#pragma unroll
    for (int ts = 0; ts < 4; ++ts)
#pragma unroll
      for (int r = 0; r < 4; ++r) tmax = fmaxf(tmax, sc[ts][r]);
    tmax = fmaxf(tmax, __shfl_xor(tmax, 16));
    tmax = fmaxf(tmax, __shfl_xor(tmax, 32));
    const float mn = fmaxf(mrow, tmax);
    const float fac = __expf(mrow - mn);
    mrow = mn;
    float psum = 0.f;
#pragma unroll
    for (int ts = 0; ts < 4; ++ts) {
      const float p0 = __expf(sc[ts][0] - mn), p1 = __expf(sc[ts][1] - mn);
      const float p2 = __expf(sc[ts][2] - mn), p3 = __expf(sc[ts][3] - mn);
      psum += (p0 + p1) + (p2 + p3);
      unsigned short h0, l0, h1, l1, h2, l2, h3, l3;
      split2(p0, h0, l0); split2(p1, h1, l1); split2(p2, h2, l2); split2(p3, h3, l3);
      const int ti = ts * 16 + kg * 4;
      unsigned* wh = reinterpret_cast<unsigned*>(&php[n16 * PST + ti]);
      unsigned* wl = reinterpret_cast<unsigned*>(&plp[n16 * PST + ti]);
      wh[0] = pack2(h0, h1); wh[1] = pack2(h2, h3);
      wl[0] = pack2(l0, l1); wl[1] = pack2(l2, l3);
    }
    lrow = lrow * fac + psum;

    float facr[4];
#pragma unroll
    for (int r = 0; r < 4; ++r) facr[r] = __shfl(fac, kg * 4 + r);
#pragma unroll
    for (int ds = 0; ds < 3; ++ds)
#pragma unroll
      for (int r = 0; r < 4; ++r) accO[ds][r] *= facr[r];

#pragma unroll
    for (int c = 0; c < 2; ++c) {
      const bf16x8 pah = *reinterpret_cast<const bf16x8*>(&php[n16 * PST + c * 32 + kg * 8]);
      const bf16x8 pal = *reinterpret_cast<const bf16x8*>(&plp[n16 * PST + c * 32 + kg * 8]);
#pragma unroll
      for (int ds = 0; ds < 3; ++ds) {
        const size_t vb = (size_t)(h * 48 + ds * 16 + n16) * 1024 + t0 + c * 32 + kg * 8;
        const bf16x8 vh = *reinterpret_cast<const bf16x8*>(vt_hi + vb);
        const bf16x8 vl = *reinterpret_cast<const bf16x8*>(vt_lo + vb);
        accO[ds] = __builtin_amdgcn_mfma_f32_16x16x32_bf16(pah, vh, accO[ds], 0, 0, 0);
        accO[ds] = __builtin_amdgcn_mfma_f32_16x16x32_bf16(pah, vl, accO[ds], 0, 0, 0);
        accO[ds] = __builtin_amdgcn_mfma_f32_16x16x32_bf16(pal, vh, accO[ds], 0, 0, 0);
      }
    }
  }

  lrow += __shfl_xor(lrow, 16);
  lrow += __shfl_xor(lrow, 32);
  const float rl = 1.f / lrow;
  float rlr[4];
#pragma unroll
  for (int r = 0; r < 4; ++r) rlr[r] = __shfl(rl, kg * 4 + r);
#pragma unroll
  for (int ds = 0; ds < 3; ++ds)
#pragma unroll
    for (int r = 0; r < 4; ++r) {
      const size_t idx = (size_t)(q0 + kg * 4 + r) * D + h * 48 + ds * 16 + n16;
      const float o = accO[ds][r] * rlr[r];
      const float a = o * sigmoidf_(g[idx]);
      unsigned short hh, ll;
      split2(a, hh, ll);
      a_hi[idx] = hh;
      a_lo[idx] = ll;
    }
}

// outproj (unchanged)
__global__ __launch_bounds__(256)
void outproj_mfma_kernel(const unsigned short* __restrict__ a_hi,
                         const unsigned short* __restrict__ a_lo,
                         const unsigned short* __restrict__ w_hi,
                         const unsigned short* __restrict__ w_lo,
                         float* __restrict__ out) {
  const int wid = blockIdx.x * 4 + (threadIdx.x >> 6);
  const int m0 = (wid / 24) * 32, n0 = (wid % 24) * 32;
  f32x4 a00 = {0.f, 0.f, 0.f, 0.f}, a01 = a00, a10 = a00, a11 = a00;
  mfma_core32(a_hi, a_lo, w_hi + (size_t)4 * D * D, w_lo + (size_t)4 * D * D,
              m0, n0, a00, a01, a10, a11);
  const int lane = threadIdx.x & 63;
  const int r16 = lane & 15, kg = lane >> 4;
#pragma unroll
  for (int r = 0; r < 4; ++r) {
    const int row0 = m0 + kg * 4 + r;
    out[(size_t)row0 * D + n0 + r16] = a00[r];
    out[(size_t)row0 * D + n0 + 16 + r16] = a01[r];
    out[(size_t)(row0 + 16) * D + n0 + r16] = a10[r];
    out[(size_t)(row0 + 16) * D + n0 + 16 + r16] = a11[r];
  }
}

extern "C" void kernel_launch(void* const* d_in, const int* in_sizes, int n_in,
                              void* d_out, int out_size, void* d_ws, size_t ws_size,
                              hipStream_t stream) {
  const float* s    = (const float*)d_in[0];
  const float* z    = (const float*)d_in[1];
  const float* Wq   = (const float*)d_in[2];
  const float* bq   = (const float*)d_in[3];
  const float* Wk   = (const float*)d_in[4];
  const float* Wv   = (const float*)d_in[5];
  const float* Wg   = (const float*)d_in[6];
  const float* ln_w = (const float*)d_in[7];
  const float* ln_b = (const float*)d_in[8];
  const float* Wz   = (const float*)d_in[9];
  const float* Wo   = (const float*)d_in[10];
  float* out = (float*)d_out;

  // workspace layout (identical to round 12)
  float* g_ws    = (float*)d_ws;                                  // S*D f32
  float* bias_ws = g_ws + (size_t)S * D;                          // H*S*S f32
  unsigned short* wzwb_ws = (unsigned short*)(bias_ws + (size_t)H * S * S);  // 2048 u16
  float* s12_ws  = bias_ws + (size_t)H * S * S + 1024;            // 32 f32
  unsigned short* s_hi = (unsigned short*)(s12_ws + 32);
  unsigned short* s_lo = s_hi + (size_t)S * D;
  unsigned short* w_hi = s_lo + (size_t)S * D;
  unsigned short* w_lo = w_hi + (size_t)5 * D * D;
  unsigned short* a_hi = w_lo + (size_t)5 * D * D;
  unsigned short* a_lo = a_hi + (size_t)S * D;
  unsigned short* q_hi = a_lo + (size_t)S * D;                    // [S][1024] padded
  unsigned short* q_lo = q_hi + (size_t)S * 1024;
  unsigned short* k_hi = q_lo + (size_t)S * 1024;
  unsigned short* k_lo = k_hi + (size_t)S * 1024;
  unsigned short* vt_hi = k_lo + (size_t)S * 1024;                // [768][1024]
  unsigned short* vt_lo = vt_hi + (size_t)D * 1024;

  // A) splits + pb_prep (one launch)
  prep_kernel<<<dim3(769, 6), 256, 0, stream>>>(s, Wq, Wk, Wv, Wg, Wo,
                                                s_hi, s_lo, w_hi, w_lo,
                                                Wz, ln_w, ln_b, wzwb_ws, s12_ws);
  // B) fused pair_bias + qkvg + padzero (one launch, overlapped)
  main_fused_kernel<<<5120, 256, 0, stream>>>(z, wzwb_ws, s12_ws, bias_ws,
                                              s_hi, s_lo, w_hi, w_lo, bq,
                                              q_hi, q_lo, k_hi, k_lo, vt_hi, vt_lo, g_ws);
  // C) MFMA flash attention (gate fused)
  attn_kernel<<<dim3(H * (S / 64)), 256, 0, stream>>>(q_hi, q_lo, k_hi, k_lo,
                                                      vt_hi, vt_lo, bias_ws, g_ws,
                                                      a_hi, a_lo);
  // D) output projection
  outproj_mfma_kernel<<<192, 256, 0, stream>>>(a_hi, a_lo, w_hi, w_lo, out);
}